// Round 3
// baseline (879.784 us; speedup 1.0000x reference)
//
#include <hip/hip_runtime.h>
#include <hip/hip_bf16.h>
#include <stdint.h>

// Problem: B=4, S=1024, HID=768, H=12, D=64
#define S_LEN 1024
#define NHEAD 12
#define NQ 3145728LL  // B*H*S*D elements per Q/K/V matrix

// d_out element offsets (fp32), reference return order:
// context[4,1024,768], attention_scores[4,12,1024,1024], value_scores,
// context_score(scalar), query_scores, key_scores
static constexpr long long OFF_ATT = 3145728LL;
static constexpr long long OFF_VAL = 53477376LL;
static constexpr long long OFF_CSC = 103809024LL;
static constexpr long long OFF_QRY = 103809025LL;  // odd base -> dword stores
static constexpr long long OFF_KEY = 154140673LL;  // odd base -> dword stores

static constexpr long long WS_VT = 9437184LL;  // vt after qkv (3*NQ)

typedef short bf16x8 __attribute__((ext_vector_type(8)));
typedef float f32x4 __attribute__((ext_vector_type(4)));

__device__ __forceinline__ unsigned short f2bf(float f) {
  return __builtin_bit_cast(unsigned short, __float2bfloat16(f));
}
__device__ __forceinline__ uint32_t pk2(float a, float b) {
  return (uint32_t)f2bf(a) | ((uint32_t)f2bf(b) << 16);
}
__device__ __forceinline__ uint4 cvt8(float4 a, float4 b) {
  return make_uint4(pk2(a.x, a.y), pk2(a.z, a.w), pk2(b.x, b.y), pk2(b.z, b.w));
}
// XOR swizzle on 16B chunks within a row; stride >= 128 bytes.
__device__ __forceinline__ uint32_t swz(uint32_t row, uint32_t col_bytes, uint32_t stride) {
  return row * stride + (col_bytes ^ ((row & 7u) << 4));
}
#define MFMA16(a, b, c) __builtin_amdgcn_mfma_f32_16x16x32_bf16((a), (b), (c), 0, 0, 0)

// ---------------------------------------------------------------------------
// Kernel 1: Y = X @ W^T + bias (fp32 in, bf16 staged). 128x128 tile, BK=64.
// Writes bf16 Q/K/V [B,H,S,D] and Vt [B,H,D,S]. Grid (32, 18); block per mat.
// ---------------------------------------------------------------------------
__global__ __launch_bounds__(256) void qkv_gemm_kernel(
    const float* __restrict__ X,
    const float* __restrict__ Wq, const float* __restrict__ Wk,
    const float* __restrict__ Wv,
    const float* __restrict__ bq, const float* __restrict__ bk,
    const float* __restrict__ bv,
    unsigned short* __restrict__ qkv, unsigned short* __restrict__ vtout)
{
  __shared__ char lds[32768];
  const int t = threadIdx.x;
  const int lane = t & 63, w = t >> 6;
  const int g = lane >> 4, l15 = lane & 15;
  const int m0 = blockIdx.x * 128;
  const int mat = blockIdx.y / 6;
  const int n0 = (blockIdx.y % 6) * 128;
  const float* W  = mat == 0 ? Wq : (mat == 1 ? Wk : Wv);
  const float* Bv = mat == 0 ? bq : (mat == 1 ? bk : bv);
  const int wm = w >> 1, wn = w & 1;
  const int srow = t >> 1, half = t & 1;

  f32x4 acc[4][4] = {};

  for (int kt = 0; kt < 12; ++kt) {
    __syncthreads();
    {
      const float4* ax = (const float4*)(X + (size_t)(m0 + srow) * 768 + kt * 64 + half * 32);
      const float4* bx = (const float4*)(W + (size_t)(n0 + srow) * 768 + kt * 64 + half * 32);
      #pragma unroll
      for (int j = 0; j < 4; ++j) {
        float4 a0 = ax[2 * j], a1 = ax[2 * j + 1];
        *(uint4*)(lds + swz(srow, half * 64 + j * 16, 128)) = cvt8(a0, a1);
        float4 b0 = bx[2 * j], b1 = bx[2 * j + 1];
        *(uint4*)(lds + 16384 + swz(srow, half * 64 + j * 16, 128)) = cvt8(b0, b1);
      }
    }
    __syncthreads();
    #pragma unroll
    for (int kk = 0; kk < 2; ++kk) {
      bf16x8 af[4], bfr[4];
      #pragma unroll
      for (int mi = 0; mi < 4; ++mi)
        af[mi] = *(const bf16x8*)(lds + swz(wm * 64 + mi * 16 + l15, kk * 64 + g * 16, 128));
      #pragma unroll
      for (int nj = 0; nj < 4; ++nj)
        bfr[nj] = *(const bf16x8*)(lds + 16384 + swz(wn * 64 + nj * 16 + l15, kk * 64 + g * 16, 128));
      #pragma unroll
      for (int mi = 0; mi < 4; ++mi)
        #pragma unroll
        for (int nj = 0; nj < 4; ++nj)
          acc[mi][nj] = MFMA16(af[mi], bfr[nj], acc[mi][nj]);
    }
  }

  #pragma unroll
  for (int mi = 0; mi < 4; ++mi) {
    #pragma unroll
    for (int nj = 0; nj < 4; ++nj) {
      const int nc = n0 + wn * 64 + nj * 16 + l15;  // [0,768)
      const int h = nc >> 6, d = nc & 63;
      const float bias = Bv[nc];
      const int mbase = m0 + wm * 64 + mi * 16 + g * 4;
      const int b = mbase >> 10, s = mbase & 1023;
      unsigned short u[4];
      #pragma unroll
      for (int r = 0; r < 4; ++r) {
        u[r] = f2bf(acc[mi][nj][r] + bias);
        qkv[(size_t)mat * NQ + (((size_t)(b * NHEAD + h)) * S_LEN + (s + r)) * 64 + d] = u[r];
      }
      if (mat == 2) {
        *(ushort4*)(vtout + (((size_t)(b * NHEAD + h)) * 64 + d) * S_LEN + s) =
            make_ushort4(u[0], u[1], u[2], u[3]);
      }
    }
  }
}

// ---------------------------------------------------------------------------
// Kernel 2: scores writer. Block = 32 rows x 1024 cols of one score matrix.
// Full-row f32 staging in LDS -> dense 4KB-row streaming stores.
// Att blocks also do exact softmax + PV + context. Grid 6144 = 48bh * 128.
// Dyn LDS 102528B: STG 64K | chunk dbuf 2x16K | A 4K | red 128B.
// ---------------------------------------------------------------------------
__global__ __launch_bounds__(256, 1) void scores_writer_kernel(
    const unsigned short* __restrict__ qkv, const unsigned short* __restrict__ vt,
    const float* __restrict__ mask, float* __restrict__ out)
{
  extern __shared__ char lds[];
  char* STG = lds;                        // 65536: [16][1024] f32, XOR-swizzled
  char* CB0 = lds + 65536;                // 16384: chunk buf 0 (bf16 [128][64] swz128)
  char* CB1 = lds + 81920;                // 16384: chunk buf 1
  char* ALB = lds + 98304;                // 4096: A panel bf16 [32][64] swz128
  float* red = (float*)(lds + 102400);    // [16] rowmax | [16] rowsum

  const int t = threadIdx.x, lane = t & 63, wv = t >> 6;
  const int g = lane >> 4, l15 = lane & 15;
  const int bid = blockIdx.x;
  if (bid == 0 && t == 0) out[OFF_CSC] = 0.f;

  const int bh = bid >> 7, sub = bid & 127;
  const int b = bh / NHEAD, h = bh % NHEAD;
  const bool is_att = (sub & 3) == 0;
  int rb, typ;
  if (is_att) { rb = sub >> 2; typ = -1; }
  else { const int sidx = sub - (sub >> 2) - 1; typ = sidx >> 5; rb = sidx & 31; }
  const int rows0 = rb * 32;

  const unsigned short* Apan;
  const unsigned short* Bmat;
  float* outbase;
  if (is_att) {
    Apan = qkv + (size_t)bh * 65536 + (size_t)rows0 * 64;   // Q rows
    Bmat = qkv + NQ + (size_t)bh * 65536;                   // K
    outbase = out + OFF_ATT + (size_t)bh * 1048576;
  } else {
    const unsigned short* M = qkv + (size_t)typ * NQ + (size_t)bh * 65536;
    Apan = M + (size_t)rows0 * 64;
    Bmat = M;
    outbase = out + (typ == 0 ? OFF_QRY : (typ == 1 ? OFF_KEY : OFF_VAL)) +
              (size_t)bh * 1048576;
  }
  const bool vec4 = is_att || typ == 2;   // 16B-aligned output base?
  const float* mrow = mask + b * S_LEN;

  // Load A panel (32x64 bf16) and preload chunk 0.
  {
    const int row = t >> 3, off = t & 7;
    *(uint4*)(ALB + swz(row, off * 16, 128)) = *(const uint4*)(Apan + (size_t)row * 64 + off * 8);
  }
  const int crow = t >> 1, ch = t & 1;
  {
    const unsigned short* src = Bmat + (size_t)crow * 64 + ch * 32;
    #pragma unroll
    for (int j = 0; j < 4; ++j)
      *(uint4*)(CB0 + swz(crow, ch * 64 + j * 16, 128)) = *(const uint4*)(src + j * 8);
  }
  __syncthreads();

  f32x4 a1[8][2];  // mi=1 accs held in regs until second half

  // ---- S-phase: 8 chunks of 128 cols, double-buffered ----
  #pragma unroll
  for (int nc = 0; nc < 8; ++nc) {
    char* cur = (nc & 1) ? CB1 : CB0;
    if (nc < 7) {
      char* nxt = (nc & 1) ? CB0 : CB1;
      const unsigned short* src = Bmat + (size_t)(nc + 1) * 8192 + (size_t)crow * 64 + ch * 32;
      #pragma unroll
      for (int j = 0; j < 4; ++j)
        *(uint4*)(nxt + swz(crow, ch * 64 + j * 16, 128)) = *(const uint4*)(src + j * 8);
    }
    f32x4 acc[2][2] = {};
    #pragma unroll
    for (int kk = 0; kk < 2; ++kk) {
      bf16x8 af[2], bfr[2];
      af[0] = *(const bf16x8*)(ALB + swz(l15, kk * 64 + g * 16, 128));
      af[1] = *(const bf16x8*)(ALB + swz(16 + l15, kk * 64 + g * 16, 128));
      bfr[0] = *(const bf16x8*)(cur + swz(wv * 32 + l15, kk * 64 + g * 16, 128));
      bfr[1] = *(const bf16x8*)(cur + swz(wv * 32 + 16 + l15, kk * 64 + g * 16, 128));
      #pragma unroll
      for (int mi = 0; mi < 2; ++mi)
        #pragma unroll
        for (int nj = 0; nj < 2; ++nj)
          acc[mi][nj] = MFMA16(af[mi], bfr[nj], acc[mi][nj]);
    }
    #pragma unroll
    for (int nj = 0; nj < 2; ++nj) {
      const int col = nc * 128 + wv * 32 + nj * 16 + l15;
      const float mv = is_att ? mrow[col] : 0.f;
      #pragma unroll
      for (int r = 0; r < 4; ++r) {
        const int row = g * 4 + r;
        *(float*)(STG + row * 4096 + ((col * 4) ^ ((row & 7) << 4))) =
            acc[0][nj][r] * 0.125f + mv;
      }
      a1[nc][nj] = acc[1][nj];
    }
    __syncthreads();
  }

  // ---- two 16-row halves ----
  for (int hh = 0; hh < 2; ++hh) {
    if (hh == 1) {
      __syncthreads();  // protect STG readers of first half
      #pragma unroll
      for (int nc = 0; nc < 8; ++nc)
        #pragma unroll
        for (int nj = 0; nj < 2; ++nj) {
          const int col = nc * 128 + wv * 32 + nj * 16 + l15;
          const float mv = is_att ? mrow[col] : 0.f;
          #pragma unroll
          for (int r = 0; r < 4; ++r) {
            const int row = g * 4 + r;
            *(float*)(STG + row * 4096 + ((col * 4) ^ ((row & 7) << 4))) =
                a1[nc][nj][r] * 0.125f + mv;
          }
        }
      __syncthreads();
    }

    if (is_att) {
      // exact row softmax stats: 16 threads per row
      const int rr = t >> 4, s16 = t & 15;
      const int sw = (rr & 7) << 4;
      float mx = -1e30f;
      #pragma unroll
      for (int i = 0; i < 16; ++i) {
        const int c16 = (s16 + i * 16) * 16;  // 16B chunk byte offset
        f32x4 v = *(const f32x4*)(STG + rr * 4096 + (c16 ^ sw));
        mx = fmaxf(mx, fmaxf(fmaxf(v[0], v[1]), fmaxf(v[2], v[3])));
      }
      mx = fmaxf(mx, __shfl_xor(mx, 1));
      mx = fmaxf(mx, __shfl_xor(mx, 2));
      mx = fmaxf(mx, __shfl_xor(mx, 4));
      mx = fmaxf(mx, __shfl_xor(mx, 8));
      float sm = 0.f;
      #pragma unroll
      for (int i = 0; i < 16; ++i) {
        const int c16 = (s16 + i * 16) * 16;
        f32x4 v = *(const f32x4*)(STG + rr * 4096 + (c16 ^ sw));
        sm += __expf(v[0] - mx) + __expf(v[1] - mx) + __expf(v[2] - mx) + __expf(v[3] - mx);
      }
      sm += __shfl_xor(sm, 1);
      sm += __shfl_xor(sm, 2);
      sm += __shfl_xor(sm, 4);
      sm += __shfl_xor(sm, 8);
      if (s16 == 0) { red[rr] = mx; red[16 + rr] = sm; }
      __syncthreads();
    }

    // ---- dense row stores (wave w: rows w*4 .. w*4+3) ----
    const int growb = rows0 + hh * 16;
    if (vec4) {
      #pragma unroll
      for (int j = 0; j < 4; ++j) {
        const int lr = wv * 4 + j;
        const int sw = (lr & 7) << 4;
        float* rp = outbase + (size_t)(growb + lr) * 1024;
        #pragma unroll
        for (int i = 0; i < 4; ++i) {
          f32x4 v = *(const f32x4*)(STG + lr * 4096 + ((lane * 16 + i * 1024) ^ sw));
          *(f32x4*)(rp + lane * 4 + i * 256) = v;
        }
      }
    } else {
      #pragma unroll
      for (int j = 0; j < 4; ++j) {
        const int lr = wv * 4 + j;
        const int sw = (lr & 7) << 4;
        float* rp = outbase + (size_t)(growb + lr) * 1024;
        #pragma unroll
        for (int i = 0; i < 16; ++i) {
          const int col = i * 64 + lane;
          rp[col] = *(const float*)(STG + lr * 4096 + ((col * 4) ^ sw));
        }
      }
    }

    if (is_att) {
      // ---- PV: waves split the k range (256 each); V frags from global vt ----
      f32x4 accO[4] = {};
      const unsigned short* vtg = vt + (size_t)bh * 65536;
      const int k0w = wv * 256;
      const float m_ = red[l15];
      #pragma unroll
      for (int ks = 0; ks < 8; ++ks) {
        const int k0 = k0w + ks * 32 + g * 8;
        const int sw = (l15 & 7) << 4;
        f32x4 pa = *(const f32x4*)(STG + l15 * 4096 + (((k0 >> 2) * 16) ^ sw));
        f32x4 pb = *(const f32x4*)(STG + l15 * 4096 + ((((k0 >> 2) + 1) * 16) ^ sw));
        uint32_t w0 = pk2(__expf(pa[0] - m_), __expf(pa[1] - m_));
        uint32_t w1 = pk2(__expf(pa[2] - m_), __expf(pa[3] - m_));
        uint32_t w2 = pk2(__expf(pb[0] - m_), __expf(pb[1] - m_));
        uint32_t w3 = pk2(__expf(pb[2] - m_), __expf(pb[3] - m_));
        bf16x8 pfr;
        *(uint4*)&pfr = make_uint4(w0, w1, w2, w3);
        #pragma unroll
        for (int nj = 0; nj < 4; ++nj) {
          bf16x8 vf = *(const bf16x8*)(vtg + (size_t)(nj * 16 + l15) * 1024 + k0);
          accO[nj] = MFMA16(pfr, vf, accO[nj]);
        }
      }
      __syncthreads();
      // partial O -> STG [wv][16][64] f32
      #pragma unroll
      for (int nj = 0; nj < 4; ++nj)
        #pragma unroll
        for (int r = 0; r < 4; ++r)
          *(float*)(STG + wv * 4096 + (g * 4 + r) * 256 + (nj * 16 + l15) * 4) = accO[nj][r];
      __syncthreads();
      // context: sum partials, normalize, store
      const int rr = t >> 4, d0 = (t & 15) * 4;
      f32x4 o = *(const f32x4*)(STG + rr * 256 + d0 * 4);
      #pragma unroll
      for (int w2 = 1; w2 < 4; ++w2)
        o += *(const f32x4*)(STG + w2 * 4096 + rr * 256 + d0 * 4);
      o *= (1.f / red[16 + rr]);
      *(f32x4*)(out + ((size_t)(b * S_LEN) + growb + rr) * 768 + h * 64 + d0) = o;
    }
  }
}

extern "C" void kernel_launch(void* const* d_in, const int* in_sizes, int n_in,
                              void* d_out, int out_size, void* d_ws, size_t ws_size,
                              hipStream_t stream) {
  (void)in_sizes; (void)n_in; (void)out_size; (void)ws_size;
  const float* X  = (const float*)d_in[0];
  const float* mk = (const float*)d_in[1];
  const float* Wq = (const float*)d_in[2];
  const float* bq = (const float*)d_in[3];
  const float* Wk = (const float*)d_in[4];
  const float* bk = (const float*)d_in[5];
  const float* Wv = (const float*)d_in[6];
  const float* bv = (const float*)d_in[7];
  float* out = (float*)d_out;
  unsigned short* qkv = (unsigned short*)d_ws;
  unsigned short* vt  = qkv + WS_VT;

  hipFuncSetAttribute((const void*)scores_writer_kernel,
                      hipFuncAttributeMaxDynamicSharedMemorySize, 102528);

  qkv_gemm_kernel<<<dim3(32, 18), 256, 0, stream>>>(X, Wq, Wk, Wv, bq, bk, bv, qkv, vt);
  scores_writer_kernel<<<6144, 256, 102528, stream>>>(qkv, vt, mk, out);
}

// Round 4
// 651.882 us; speedup vs baseline: 1.3496x; 1.3496x over previous
//
#include <hip/hip_runtime.h>
#include <hip/hip_bf16.h>
#include <stdint.h>

// Problem: B=4, S=1024, HID=768, H=12, D=64
#define S_LEN 1024
#define NHEAD 12
#define NQ 3145728LL  // B*H*S*D elements per Q/K/V matrix

// d_out element offsets (fp32), reference return order:
// context[4,1024,768], attention_scores[4,12,1024,1024], value_scores,
// context_score(scalar), query_scores, key_scores
static constexpr long long OFF_ATT = 3145728LL;
static constexpr long long OFF_VAL = 53477376LL;
static constexpr long long OFF_CSC = 103809024LL;
static constexpr long long OFF_QRY = 103809025LL;  // odd base -> dword stores
static constexpr long long OFF_KEY = 154140673LL;  // odd base -> dword stores

static constexpr long long WS_VT = 9437184LL;  // vt after qkv (3*NQ)

typedef short bf16x8 __attribute__((ext_vector_type(8)));
typedef float f32x4 __attribute__((ext_vector_type(4)));

__device__ __forceinline__ unsigned short f2bf(float f) {
  return __builtin_bit_cast(unsigned short, __float2bfloat16(f));
}
__device__ __forceinline__ uint32_t pk2(float a, float b) {
  return (uint32_t)f2bf(a) | ((uint32_t)f2bf(b) << 16);
}
__device__ __forceinline__ uint4 cvt8(float4 a, float4 b) {
  return make_uint4(pk2(a.x, a.y), pk2(a.z, a.w), pk2(b.x, b.y), pk2(b.z, b.w));
}
// XOR swizzle on 16B chunks within a row; stride >= 128 bytes.
__device__ __forceinline__ uint32_t swz(uint32_t row, uint32_t col_bytes, uint32_t stride) {
  return row * stride + (col_bytes ^ ((row & 7u) << 4));
}
#define MFMA16(a, b, c) __builtin_amdgcn_mfma_f32_16x16x32_bf16((a), (b), (c), 0, 0, 0)

// ---------------------------------------------------------------------------
// Kernel 1: Y = X @ W^T + bias (fp32 in, bf16 staged). 128x128 tile, BK=64.
// Writes bf16 Q/K/V [B,H,S,D] and Vt [B,H,D,S]. Grid (32, 18).
// ---------------------------------------------------------------------------
__global__ __launch_bounds__(256) void qkv_gemm_kernel(
    const float* __restrict__ X,
    const float* __restrict__ Wq, const float* __restrict__ Wk,
    const float* __restrict__ Wv,
    const float* __restrict__ bq, const float* __restrict__ bk,
    const float* __restrict__ bv,
    unsigned short* __restrict__ qkv, unsigned short* __restrict__ vtout)
{
  __shared__ char lds[32768];
  const int t = threadIdx.x;
  const int lane = t & 63, w = t >> 6;
  const int g = lane >> 4, l15 = lane & 15;
  const int m0 = blockIdx.x * 128;
  const int mat = blockIdx.y / 6;
  const int n0 = (blockIdx.y % 6) * 128;
  const float* W  = mat == 0 ? Wq : (mat == 1 ? Wk : Wv);
  const float* Bv = mat == 0 ? bq : (mat == 1 ? bk : bv);
  const int wm = w >> 1, wn = w & 1;
  const int srow = t >> 1, half = t & 1;

  f32x4 acc[4][4] = {};

  for (int kt = 0; kt < 12; ++kt) {
    __syncthreads();
    {
      const float4* ax = (const float4*)(X + (size_t)(m0 + srow) * 768 + kt * 64 + half * 32);
      const float4* bx = (const float4*)(W + (size_t)(n0 + srow) * 768 + kt * 64 + half * 32);
      #pragma unroll
      for (int j = 0; j < 4; ++j) {
        float4 a0 = ax[2 * j], a1 = ax[2 * j + 1];
        *(uint4*)(lds + swz(srow, half * 64 + j * 16, 128)) = cvt8(a0, a1);
        float4 b0 = bx[2 * j], b1 = bx[2 * j + 1];
        *(uint4*)(lds + 16384 + swz(srow, half * 64 + j * 16, 128)) = cvt8(b0, b1);
      }
    }
    __syncthreads();
    #pragma unroll
    for (int kk = 0; kk < 2; ++kk) {
      bf16x8 af[4], bfr[4];
      #pragma unroll
      for (int mi = 0; mi < 4; ++mi)
        af[mi] = *(const bf16x8*)(lds + swz(wm * 64 + mi * 16 + l15, kk * 64 + g * 16, 128));
      #pragma unroll
      for (int nj = 0; nj < 4; ++nj)
        bfr[nj] = *(const bf16x8*)(lds + 16384 + swz(wn * 64 + nj * 16 + l15, kk * 64 + g * 16, 128));
      #pragma unroll
      for (int mi = 0; mi < 4; ++mi)
        #pragma unroll
        for (int nj = 0; nj < 4; ++nj)
          acc[mi][nj] = MFMA16(af[mi], bfr[nj], acc[mi][nj]);
    }
  }

  #pragma unroll
  for (int mi = 0; mi < 4; ++mi) {
    #pragma unroll
    for (int nj = 0; nj < 4; ++nj) {
      const int nc = n0 + wn * 64 + nj * 16 + l15;  // [0,768)
      const int h = nc >> 6, d = nc & 63;
      const float bias = Bv[nc];
      const int mbase = m0 + wm * 64 + mi * 16 + g * 4;
      const int b = mbase >> 10, s = mbase & 1023;
      unsigned short u[4];
      #pragma unroll
      for (int r = 0; r < 4; ++r) {
        u[r] = f2bf(acc[mi][nj][r] + bias);
        qkv[(size_t)mat * NQ + (((size_t)(b * NHEAD + h)) * S_LEN + (s + r)) * 64 + d] = u[r];
      }
      if (mat == 2) {
        *(ushort4*)(vtout + (((size_t)(b * NHEAD + h)) * 64 + d) * S_LEN + s) =
            make_ushort4(u[0], u[1], u[2], u[3]);
      }
    }
  }
}

// ---------------------------------------------------------------------------
// Device part: sym scores G = A A^T / 8. Barrier-free, LDS-free.
// One wave owns 16 m-rows (A-frags in regs); loops n over 1024 in 16-steps,
// B-frags read directly from global (L2-resident). Transposed stores
// (G symmetric, bitwise-identical MFMA sums) give 64B/row line-complete runs.
// sid in [0, 2304): typ = sid/768, bh = (sid%768)>>4, mblk = sid&15.
// ---------------------------------------------------------------------------
__device__ __forceinline__ void sym_part(
    int sid, const unsigned short* __restrict__ qkv, float* __restrict__ out)
{
  const int t = threadIdx.x, lane = t & 63, wv = t >> 6;
  const int g = lane >> 4, l15 = lane & 15;
  const int typ = sid / 768, r = sid % 768;
  const int bh = r >> 4, mb = r & 15;
  const int m0w = mb * 64 + wv * 16;
  const unsigned short* M = qkv + (size_t)typ * NQ + (size_t)bh * 65536;

  const bf16x8 af0 = *(const bf16x8*)(M + (size_t)(m0w + l15) * 64 + g * 8);
  const bf16x8 af1 = *(const bf16x8*)(M + (size_t)(m0w + l15) * 64 + 32 + g * 8);

  if (typ == 2) {
    float* O = out + OFF_VAL + (size_t)bh * 1048576 + m0w + g * 4;
    #pragma unroll 4
    for (int n0 = 0; n0 < 1024; n0 += 16) {
      const bf16x8 b0 = *(const bf16x8*)(M + (size_t)(n0 + l15) * 64 + g * 8);
      const bf16x8 b1 = *(const bf16x8*)(M + (size_t)(n0 + l15) * 64 + 32 + g * 8);
      f32x4 acc = {};
      acc = MFMA16(af0, b0, acc);
      acc = MFMA16(af1, b1, acc);
      acc *= 0.125f;
      *(f32x4*)(O + (size_t)(n0 + l15) * 1024) = acc;
    }
  } else {
    float* O = out + (typ == 0 ? OFF_QRY : OFF_KEY) + (size_t)bh * 1048576 + m0w + g * 4;
    #pragma unroll 4
    for (int n0 = 0; n0 < 1024; n0 += 16) {
      const bf16x8 b0 = *(const bf16x8*)(M + (size_t)(n0 + l15) * 64 + g * 8);
      const bf16x8 b1 = *(const bf16x8*)(M + (size_t)(n0 + l15) * 64 + 32 + g * 8);
      f32x4 acc = {};
      acc = MFMA16(af0, b0, acc);
      acc = MFMA16(af1, b1, acc);
      #pragma unroll
      for (int rr = 0; rr < 4; ++rr)
        O[(size_t)(n0 + l15) * 1024 + rr] = acc[rr] * 0.125f;
    }
  }
}

// ---------------------------------------------------------------------------
// Device part: attention. Barrier-free; K/V frags direct from global (L2);
// wave-private LDS only for the P transpose. aid in [0,768).
// S^T = mfma(K, Q): lane owns q-row q0 + wv*16 + (lane&15).
// ---------------------------------------------------------------------------
__device__ __forceinline__ void att_part(
    char* lds, int aid, const unsigned short* __restrict__ qkv,
    const unsigned short* __restrict__ vt, const float* __restrict__ mask,
    float* __restrict__ out)
{
  const int t = threadIdx.x, lane = t & 63, wv = t >> 6;
  const int g = lane >> 4, l15 = lane & 15;
  const int bh = aid >> 4, q0 = (aid & 15) * 64;
  const int b = bh / NHEAD, h = bh % NHEAD;
  const unsigned short* Qp  = qkv + (size_t)bh * 65536;
  const unsigned short* Kp  = qkv + NQ + (size_t)bh * 65536;
  const unsigned short* Vtp = vt + (size_t)bh * 65536;
  const int qrow = q0 + wv * 16 + l15;

  bf16x8 qf0 = *(const bf16x8*)(Qp + (size_t)qrow * 64 + g * 8);
  bf16x8 qf1 = *(const bf16x8*)(Qp + (size_t)qrow * 64 + 32 + g * 8);

  float m_run = -1e30f, l_run = 0.f;
  f32x4 o[4] = {};
  float* att = out + OFF_ATT + (size_t)bh * 1048576 + (size_t)qrow * 1024;
  const float* mrow = mask + b * S_LEN;
  char* Plds = lds + wv * 4096;

  for (int kt = 0; kt < 8; ++kt) {
    // S^T[k][q]: A-frags = K rows, direct from global
    f32x4 st[8] = {};
    #pragma unroll
    for (int mi = 0; mi < 8; ++mi) {
      const unsigned short* kr = Kp + (size_t)(kt * 128 + mi * 16 + l15) * 64;
      const bf16x8 k0 = *(const bf16x8*)(kr + g * 8);
      const bf16x8 k1 = *(const bf16x8*)(kr + 32 + g * 8);
      st[mi] = MFMA16(k0, qf0, st[mi]);
      st[mi] = MFMA16(k1, qf1, st[mi]);
    }

    // scale + mask + dense score store (64B/row per instruction)
    float tmax = -1e30f;
    #pragma unroll
    for (int mi = 0; mi < 8; ++mi) {
      const f32x4 mk = *(const f32x4*)(mrow + kt * 128 + mi * 16 + g * 4);
      st[mi] = st[mi] * 0.125f + mk;
      *(f32x4*)(att + kt * 128 + mi * 16 + g * 4) = st[mi];
      #pragma unroll
      for (int rr = 0; rr < 4; ++rr) tmax = fmaxf(tmax, st[mi][rr]);
    }
    tmax = fmaxf(tmax, __shfl_xor(tmax, 16));
    tmax = fmaxf(tmax, __shfl_xor(tmax, 32));
    const float mnew = fmaxf(m_run, tmax);
    const float corr = __expf(m_run - mnew);
    float tsum = 0.f;
    #pragma unroll
    for (int mi = 0; mi < 8; ++mi)
      #pragma unroll
      for (int rr = 0; rr < 4; ++rr) {
        const float p = __expf(st[mi][rr] - mnew);
        st[mi][rr] = p;
        tsum += p;
      }
    tsum += __shfl_xor(tsum, 16);
    tsum += __shfl_xor(tsum, 32);
    l_run = l_run * corr + tsum;
    m_run = mnew;
    #pragma unroll
    for (int dj = 0; dj < 4; ++dj) o[dj] *= corr;

    // P -> bf16 -> wave-private LDS [16 q][128 k] (swizzled); no barrier
    #pragma unroll
    for (int mi = 0; mi < 8; ++mi) {
      uint2 pw = make_uint2(pk2(st[mi][0], st[mi][1]), pk2(st[mi][2], st[mi][3]));
      *(uint2*)(Plds + swz(l15, mi * 32 + g * 8, 256)) = pw;
    }
    // O^T[d][q] += Vt[d][k] P[q][k]; V frags direct from global vt
    #pragma unroll
    for (int kk2 = 0; kk2 < 4; ++kk2) {
      const bf16x8 pa = *(const bf16x8*)(Plds + swz(l15, kk2 * 64 + g * 16, 256));
      #pragma unroll
      for (int dj = 0; dj < 4; ++dj) {
        const bf16x8 vf = *(const bf16x8*)(Vtp + (size_t)(dj * 16 + l15) * 1024 +
                                           kt * 128 + kk2 * 32 + g * 8);
        o[dj] = MFMA16(vf, pa, o[dj]);
      }
    }
  }

  const float inv = 1.f / l_run;
  #pragma unroll
  for (int dj = 0; dj < 4; ++dj) {
    f32x4 v = o[dj] * inv;
    *(f32x4*)(out + ((size_t)b * S_LEN + qrow) * 768 + h * 64 + dj * 16 + g * 4) = v;
  }
}

// ---------------------------------------------------------------------------
// Kernel 2: fused streaming kernel. Grid 3072 = 2304 sym + 768 att blocks,
// att every 4th block. No __syncthreads anywhere; 16KB static LDS (P only).
// ---------------------------------------------------------------------------
__global__ __launch_bounds__(256) void fused_stream_kernel(
    const unsigned short* __restrict__ qkv, const unsigned short* __restrict__ vt,
    const float* __restrict__ mask, float* __restrict__ out)
{
  __shared__ char lds[16384];
  const int bid = blockIdx.x;
  if (bid == 0 && threadIdx.x == 0) out[OFF_CSC] = 0.f;
  if ((bid & 3) == 0) {
    att_part(lds, bid >> 2, qkv, vt, mask, out);
  } else {
    sym_part(bid - (bid >> 2) - 1, qkv, out);
  }
}

extern "C" void kernel_launch(void* const* d_in, const int* in_sizes, int n_in,
                              void* d_out, int out_size, void* d_ws, size_t ws_size,
                              hipStream_t stream) {
  (void)in_sizes; (void)n_in; (void)out_size; (void)ws_size;
  const float* X  = (const float*)d_in[0];
  const float* mk = (const float*)d_in[1];
  const float* Wq = (const float*)d_in[2];
  const float* bq = (const float*)d_in[3];
  const float* Wk = (const float*)d_in[4];
  const float* bk = (const float*)d_in[5];
  const float* Wv = (const float*)d_in[6];
  const float* bv = (const float*)d_in[7];
  float* out = (float*)d_out;
  unsigned short* qkv = (unsigned short*)d_ws;
  unsigned short* vt  = qkv + WS_VT;

  qkv_gemm_kernel<<<dim3(32, 18), 256, 0, stream>>>(X, Wq, Wk, Wv, bq, bk, bv, qkv, vt);
  fused_stream_kernel<<<3072, 256, 0, stream>>>(qkv, vt, mk, out);
}

// Round 5
// 643.398 us; speedup vs baseline: 1.3674x; 1.0132x over previous
//
#include <hip/hip_runtime.h>
#include <hip/hip_bf16.h>
#include <stdint.h>

// Problem: B=4, S=1024, HID=768, H=12, D=64
#define S_LEN 1024
#define NHEAD 12
#define NQ 3145728LL  // B*H*S*D elements per Q/K/V matrix

// d_out element offsets (fp32), reference return order:
// context[4,1024,768], attention_scores[4,12,1024,1024], value_scores,
// context_score(scalar), query_scores, key_scores
static constexpr long long OFF_ATT = 3145728LL;
static constexpr long long OFF_VAL = 53477376LL;
static constexpr long long OFF_CSC = 103809024LL;
static constexpr long long OFF_QRY = 103809025LL;  // odd base -> dword stores
static constexpr long long OFF_KEY = 154140673LL;  // odd base -> dword stores

static constexpr long long WS_VT = 9437184LL;  // vt after qkv (3*NQ)

typedef short bf16x8 __attribute__((ext_vector_type(8)));
typedef float f32x4 __attribute__((ext_vector_type(4)));

__device__ __forceinline__ unsigned short f2bf(float f) {
  return __builtin_bit_cast(unsigned short, __float2bfloat16(f));
}
__device__ __forceinline__ uint32_t pk2(float a, float b) {
  return (uint32_t)f2bf(a) | ((uint32_t)f2bf(b) << 16);
}
__device__ __forceinline__ uint4 cvt8(float4 a, float4 b) {
  return make_uint4(pk2(a.x, a.y), pk2(a.z, a.w), pk2(b.x, b.y), pk2(b.z, b.w));
}
// XOR swizzle on 16B chunks within a row; stride >= 128 bytes.
__device__ __forceinline__ uint32_t swz(uint32_t row, uint32_t col_bytes, uint32_t stride) {
  return row * stride + (col_bytes ^ ((row & 7u) << 4));
}
// Non-temporal stores: score outputs are never re-read; keep L2 for operands.
__device__ __forceinline__ void nts4(float* p, f32x4 v) {
  __builtin_nontemporal_store(v, (f32x4*)p);
}
__device__ __forceinline__ void nts1(float* p, float v) {
  __builtin_nontemporal_store(v, p);
}
#define MFMA16(a, b, c) __builtin_amdgcn_mfma_f32_16x16x32_bf16((a), (b), (c), 0, 0, 0)

// ---------------------------------------------------------------------------
// Kernel 1: Y = X @ W^T + bias (fp32 in, bf16 staged). 128x128 tile, BK=64.
// Writes bf16 Q/K/V [B,H,S,D] and Vt [B,H,D,S]. Grid (32, 18).
// ---------------------------------------------------------------------------
__global__ __launch_bounds__(256) void qkv_gemm_kernel(
    const float* __restrict__ X,
    const float* __restrict__ Wq, const float* __restrict__ Wk,
    const float* __restrict__ Wv,
    const float* __restrict__ bq, const float* __restrict__ bk,
    const float* __restrict__ bv,
    unsigned short* __restrict__ qkv, unsigned short* __restrict__ vtout)
{
  __shared__ char lds[32768];
  const int t = threadIdx.x;
  const int lane = t & 63, w = t >> 6;
  const int g = lane >> 4, l15 = lane & 15;
  const int m0 = blockIdx.x * 128;
  const int mat = blockIdx.y / 6;
  const int n0 = (blockIdx.y % 6) * 128;
  const float* W  = mat == 0 ? Wq : (mat == 1 ? Wk : Wv);
  const float* Bv = mat == 0 ? bq : (mat == 1 ? bk : bv);
  const int wm = w >> 1, wn = w & 1;
  const int srow = t >> 1, half = t & 1;

  f32x4 acc[4][4] = {};

  for (int kt = 0; kt < 12; ++kt) {
    __syncthreads();
    {
      const float4* ax = (const float4*)(X + (size_t)(m0 + srow) * 768 + kt * 64 + half * 32);
      const float4* bx = (const float4*)(W + (size_t)(n0 + srow) * 768 + kt * 64 + half * 32);
      #pragma unroll
      for (int j = 0; j < 4; ++j) {
        float4 a0 = ax[2 * j], a1 = ax[2 * j + 1];
        *(uint4*)(lds + swz(srow, half * 64 + j * 16, 128)) = cvt8(a0, a1);
        float4 b0 = bx[2 * j], b1 = bx[2 * j + 1];
        *(uint4*)(lds + 16384 + swz(srow, half * 64 + j * 16, 128)) = cvt8(b0, b1);
      }
    }
    __syncthreads();
    #pragma unroll
    for (int kk = 0; kk < 2; ++kk) {
      bf16x8 af[4], bfr[4];
      #pragma unroll
      for (int mi = 0; mi < 4; ++mi)
        af[mi] = *(const bf16x8*)(lds + swz(wm * 64 + mi * 16 + l15, kk * 64 + g * 16, 128));
      #pragma unroll
      for (int nj = 0; nj < 4; ++nj)
        bfr[nj] = *(const bf16x8*)(lds + 16384 + swz(wn * 64 + nj * 16 + l15, kk * 64 + g * 16, 128));
      #pragma unroll
      for (int mi = 0; mi < 4; ++mi)
        #pragma unroll
        for (int nj = 0; nj < 4; ++nj)
          acc[mi][nj] = MFMA16(af[mi], bfr[nj], acc[mi][nj]);
    }
  }

  #pragma unroll
  for (int mi = 0; mi < 4; ++mi) {
    #pragma unroll
    for (int nj = 0; nj < 4; ++nj) {
      const int nc = n0 + wn * 64 + nj * 16 + l15;  // [0,768)
      const int h = nc >> 6, d = nc & 63;
      const float bias = Bv[nc];
      const int mbase = m0 + wm * 64 + mi * 16 + g * 4;
      const int b = mbase >> 10, s = mbase & 1023;
      unsigned short u[4];
      #pragma unroll
      for (int r = 0; r < 4; ++r) {
        u[r] = f2bf(acc[mi][nj][r] + bias);
        qkv[(size_t)mat * NQ + (((size_t)(b * NHEAD + h)) * S_LEN + (s + r)) * 64 + d] = u[r];
      }
      if (mat == 2) {
        *(ushort4*)(vtout + (((size_t)(b * NHEAD + h)) * 64 + d) * S_LEN + s) =
            make_ushort4(u[0], u[1], u[2], u[3]);
      }
    }
  }
}

// ---------------------------------------------------------------------------
// Device part A: sym scores G = A A^T / 8 for A in {Q,K,V}.
// 128x128 tile per call; 4 waves of 64x64; LDS-tiled, 2 barriers.
// ---------------------------------------------------------------------------
__device__ __forceinline__ void sym_part(
    char* lds, int sid, const unsigned short* __restrict__ qkv,
    float* __restrict__ out)
{
  const int t = threadIdx.x;
  const int lane = t & 63, w = t >> 6;
  const int g = lane >> 4, l15 = lane & 15;
  const int m0 = (sid & 7) * 128;
  const int n0 = ((sid >> 3) & 7) * 128;
  const int bz = sid >> 6;           // 0..143
  const int typ = bz / 48, bh = bz % 48;
  const unsigned short* A = qkv + (size_t)typ * NQ + (size_t)bh * (S_LEN * 64);
  const int srow = t >> 1, hf = t & 1;
  {
    const uint4* sa = (const uint4*)(A + (size_t)(m0 + srow) * 64 + hf * 32);
    #pragma unroll
    for (int j = 0; j < 4; ++j)
      *(uint4*)(lds + swz(srow, hf * 64 + j * 16, 128)) = sa[j];
    const uint4* sb = (const uint4*)(A + (size_t)(n0 + srow) * 64 + hf * 32);
    #pragma unroll
    for (int j = 0; j < 4; ++j)
      *(uint4*)(lds + 16384 + swz(srow, hf * 64 + j * 16, 128)) = sb[j];
  }
  __syncthreads();
  const int wm = w >> 1, wn = w & 1;
  f32x4 acc[4][4] = {};
  #pragma unroll
  for (int kk = 0; kk < 2; ++kk) {
    bf16x8 af[4], bfr[4];
    #pragma unroll
    for (int mi = 0; mi < 4; ++mi)
      af[mi] = *(const bf16x8*)(lds + swz(wm * 64 + mi * 16 + l15, kk * 64 + g * 16, 128));
    #pragma unroll
    for (int nj = 0; nj < 4; ++nj)
      bfr[nj] = *(const bf16x8*)(lds + 16384 + swz(wn * 64 + nj * 16 + l15, kk * 64 + g * 16, 128));
    #pragma unroll
    for (int mi = 0; mi < 4; ++mi)
      #pragma unroll
      for (int nj = 0; nj < 4; ++nj)
        acc[mi][nj] = MFMA16(af[mi], bfr[nj], acc[mi][nj]);
  }
  if (typ == 2) {
    // Symmetry trick: store frag at the TRANSPOSED location -> float4 stores.
    float* O = out + OFF_VAL + (size_t)bh * (1024ull * 1024);
    #pragma unroll
    for (int mi = 0; mi < 4; ++mi)
      #pragma unroll
      for (int nj = 0; nj < 4; ++nj) {
        f32x4 v = acc[mi][nj] * 0.125f;
        nts4(O + (size_t)(n0 + wn * 64 + nj * 16 + l15) * 1024 +
             (m0 + wm * 64 + mi * 16 + g * 4), v);
      }
  } else {
    float* O = out + (typ == 0 ? OFF_QRY : OFF_KEY) + (size_t)bh * (1024ull * 1024);
    #pragma unroll
    for (int mi = 0; mi < 4; ++mi)
      #pragma unroll
      for (int nj = 0; nj < 4; ++nj)
        #pragma unroll
        for (int r = 0; r < 4; ++r)
          nts1(O + (size_t)(m0 + wm * 64 + mi * 16 + g * 4 + r) * 1024 +
               (n0 + wn * 64 + nj * 16 + l15), acc[mi][nj][r] * 0.125f);
  }
}

// ---------------------------------------------------------------------------
// Device part B: fused attention_scores write + online softmax + context.
// S^T = mfma(K, Q) so each lane owns one q-row. fid in [0,768).
// ---------------------------------------------------------------------------
__device__ __forceinline__ void flash_part(
    char* lds, int fid, const unsigned short* __restrict__ qkv,
    const unsigned short* __restrict__ vt, const float* __restrict__ mask,
    float* __restrict__ out)
{
  const int t = threadIdx.x;
  const int lane = t & 63, w = t >> 6;
  const int g = lane >> 4, l15 = lane & 15;
  const int q0 = (fid & 15) * 64;
  const int bh = fid >> 4, b = bh / NHEAD, h = bh % NHEAD;
  const unsigned short* Qp  = qkv + (size_t)bh * (S_LEN * 64);
  const unsigned short* Kp  = qkv + NQ + (size_t)bh * (S_LEN * 64);
  const unsigned short* Vtp = vt + (size_t)bh * (S_LEN * 64);
  const int qrow = q0 + w * 16 + l15;  // this lane's q row

  bf16x8 qf[2];
  qf[0] = *(const bf16x8*)(Qp + (size_t)qrow * 64 + g * 8);
  qf[1] = *(const bf16x8*)(Qp + (size_t)qrow * 64 + 32 + g * 8);

  float m_run = -1e30f, l_run = 0.f;
  f32x4 o[4] = {};
  float* att = out + OFF_ATT + (size_t)bh * (1024ull * 1024) + (size_t)qrow * 1024;
  const float* mrow = mask + b * S_LEN;
  const int sr2 = t >> 1, hf = t & 1;  // K staging: 128 rows x 128B
  const int sr4 = t >> 2, qr = t & 3;  // Vt staging: 64 rows x 256B
  char* Plds = lds + 32768 + w * 4096;

  for (int kt = 0; kt < 8; ++kt) {
    __syncthreads();
    {
      const uint4* sk = (const uint4*)(Kp + (size_t)(kt * 128 + sr2) * 64 + hf * 32);
      #pragma unroll
      for (int j = 0; j < 4; ++j)
        *(uint4*)(lds + swz(sr2, hf * 64 + j * 16, 128)) = sk[j];
      const uint4* sv = (const uint4*)(Vtp + (size_t)sr4 * S_LEN + kt * 128 + qr * 32);
      #pragma unroll
      for (int j = 0; j < 4; ++j)
        *(uint4*)(lds + 16384 + swz(sr4, qr * 64 + j * 16, 256)) = sv[j];
    }
    __syncthreads();

    // S^T[k][q] = sum_d K[k][d] Q[q][d]
    f32x4 st[8] = {};
    #pragma unroll
    for (int kk = 0; kk < 2; ++kk)
      #pragma unroll
      for (int mi = 0; mi < 8; ++mi) {
        bf16x8 a = *(const bf16x8*)(lds + swz(mi * 16 + l15, kk * 64 + g * 16, 128));
        st[mi] = MFMA16(a, qf[kk], st[mi]);
      }

    // scale + mask + write scores (lane holds 4 consecutive k for its q row)
    float tmax = -1e30f;
    #pragma unroll
    for (int mi = 0; mi < 8; ++mi) {
      const f32x4 mk = *(const f32x4*)(mrow + kt * 128 + mi * 16 + g * 4);
      st[mi] = st[mi] * 0.125f + mk;
      nts4(att + kt * 128 + mi * 16 + g * 4, st[mi]);
      #pragma unroll
      for (int r = 0; r < 4; ++r) tmax = fmaxf(tmax, st[mi][r]);
    }
    tmax = fmaxf(tmax, __shfl_xor(tmax, 16));
    tmax = fmaxf(tmax, __shfl_xor(tmax, 32));
    const float mnew = fmaxf(m_run, tmax);
    const float corr = __expf(m_run - mnew);
    float tsum = 0.f;
    #pragma unroll
    for (int mi = 0; mi < 8; ++mi)
      #pragma unroll
      for (int r = 0; r < 4; ++r) {
        const float p = __expf(st[mi][r] - mnew);
        st[mi][r] = p;
        tsum += p;
      }
    tsum += __shfl_xor(tsum, 16);
    tsum += __shfl_xor(tsum, 32);
    l_run = l_run * corr + tsum;
    m_run = mnew;
    #pragma unroll
    for (int dj = 0; dj < 4; ++dj) o[dj] *= corr;

    // P -> bf16 -> per-wave LDS [16 q rows][128 k], swizzled
    #pragma unroll
    for (int mi = 0; mi < 8; ++mi) {
      uint2 pw = make_uint2(pk2(st[mi][0], st[mi][1]), pk2(st[mi][2], st[mi][3]));
      *(uint2*)(Plds + swz(l15, mi * 32 + g * 8, 256)) = pw;
    }
    // O^T[d][q] += sum_k Vt[d][k] P[q][k]
    #pragma unroll
    for (int kk2 = 0; kk2 < 4; ++kk2) {
      const bf16x8 pa = *(const bf16x8*)(Plds + swz(l15, kk2 * 64 + g * 16, 256));
      #pragma unroll
      for (int dj = 0; dj < 4; ++dj) {
        const bf16x8 va = *(const bf16x8*)(lds + 16384 + swz(dj * 16 + l15, kk2 * 64 + g * 16, 256));
        o[dj] = MFMA16(va, pa, o[dj]);
      }
    }
  }

  const float inv = 1.f / l_run;
  #pragma unroll
  for (int dj = 0; dj < 4; ++dj) {
    f32x4 v = o[dj] * inv;
    nts4(out + ((size_t)b * S_LEN + qrow) * 768 + h * 64 + dj * 16 + g * 4, v);
  }
}

// ---------------------------------------------------------------------------
// Kernel 2: merged sym+flash. Grid 9984 = 768*13. Every 13th block is a flash
// block so write-bound sym blocks and compute-phase flash blocks co-reside on
// each CU, hiding flash compute under the HBM write stream.
// ---------------------------------------------------------------------------
__global__ __launch_bounds__(256) void fused_scores_attn_kernel(
    const unsigned short* __restrict__ qkv, const unsigned short* __restrict__ vt,
    const float* __restrict__ mask, float* __restrict__ out)
{
  __shared__ char lds[49152];
  const int bid = blockIdx.x;
  if (bid == 9983 && threadIdx.x == 0) out[OFF_CSC] = 0.f;
  if (bid % 13 == 0) {
    flash_part(lds, bid / 13, qkv, vt, mask, out);
  } else {
    sym_part(lds, bid - bid / 13 - 1, qkv, out);
  }
}

extern "C" void kernel_launch(void* const* d_in, const int* in_sizes, int n_in,
                              void* d_out, int out_size, void* d_ws, size_t ws_size,
                              hipStream_t stream) {
  (void)in_sizes; (void)n_in; (void)out_size; (void)ws_size;
  const float* X  = (const float*)d_in[0];
  const float* mk = (const float*)d_in[1];
  const float* Wq = (const float*)d_in[2];
  const float* bq = (const float*)d_in[3];
  const float* Wk = (const float*)d_in[4];
  const float* bk = (const float*)d_in[5];
  const float* Wv = (const float*)d_in[6];
  const float* bv = (const float*)d_in[7];
  float* out = (float*)d_out;
  unsigned short* qkv = (unsigned short*)d_ws;
  unsigned short* vt  = qkv + WS_VT;

  qkv_gemm_kernel<<<dim3(32, 18), 256, 0, stream>>>(X, Wq, Wk, Wv, bq, bk, bv, qkv, vt);
  fused_scores_attn_kernel<<<9984, 256, 0, stream>>>(qkv, vt, mk, out);
}

// Round 6
// 425.803 us; speedup vs baseline: 2.0662x; 1.5110x over previous
//
#include <hip/hip_runtime.h>
#include <hip/hip_bf16.h>
#include <stdint.h>

// Problem: B=4, S=1024, HID=768, H=12, D=64
#define S_LEN 1024
#define NHEAD 12
#define NQ 3145728LL  // B*H*S*D elements per Q/K/V matrix

// d_out element offsets (fp32), reference return order:
// context[4,1024,768], attention_scores[4,12,1024,1024], value_scores,
// context_score(scalar), query_scores, key_scores
static constexpr long long OFF_ATT = 3145728LL;
static constexpr long long OFF_VAL = 53477376LL;
static constexpr long long OFF_CSC = 103809024LL;
static constexpr long long OFF_QRY = 103809025LL;  // odd base -> dword stores
static constexpr long long OFF_KEY = 154140673LL;  // odd base -> dword stores

static constexpr long long WS_VT = 9437184LL;  // vt after qkv (3*NQ)

typedef short bf16x8 __attribute__((ext_vector_type(8)));
typedef float f32x4 __attribute__((ext_vector_type(4)));
typedef float f32x2 __attribute__((ext_vector_type(2)));

__device__ __forceinline__ unsigned short f2bf(float f) {
  return __builtin_bit_cast(unsigned short, __float2bfloat16(f));
}
__device__ __forceinline__ uint32_t pk2(float a, float b) {
  return (uint32_t)f2bf(a) | ((uint32_t)f2bf(b) << 16);
}
__device__ __forceinline__ uint4 cvt8(float4 a, float4 b) {
  return make_uint4(pk2(a.x, a.y), pk2(a.z, a.w), pk2(b.x, b.y), pk2(b.z, b.w));
}
// XOR swizzle on 16B chunks within a row; stride >= 128 bytes.
__device__ __forceinline__ uint32_t swz(uint32_t row, uint32_t col_bytes, uint32_t stride) {
  return row * stride + (col_bytes ^ ((row & 7u) << 4));
}
#define MFMA16(a, b, c) __builtin_amdgcn_mfma_f32_16x16x32_bf16((a), (b), (c), 0, 0, 0)

// ---------------------------------------------------------------------------
// Kernel 1: Y = X @ W^T + bias (fp32 in, bf16 staged). 128x128 tile, BK=64.
// Writes bf16 Q/K/V [B,H,S,D] and Vt [B,H,D,S]. Grid (32, 18).
// ---------------------------------------------------------------------------
__global__ __launch_bounds__(256) void qkv_gemm_kernel(
    const float* __restrict__ X,
    const float* __restrict__ Wq, const float* __restrict__ Wk,
    const float* __restrict__ Wv,
    const float* __restrict__ bq, const float* __restrict__ bk,
    const float* __restrict__ bv,
    unsigned short* __restrict__ qkv, unsigned short* __restrict__ vtout)
{
  __shared__ char lds[32768];
  const int t = threadIdx.x;
  const int lane = t & 63, w = t >> 6;
  const int g = lane >> 4, l15 = lane & 15;
  const int m0 = blockIdx.x * 128;
  const int mat = blockIdx.y / 6;
  const int n0 = (blockIdx.y % 6) * 128;
  const float* W  = mat == 0 ? Wq : (mat == 1 ? Wk : Wv);
  const float* Bv = mat == 0 ? bq : (mat == 1 ? bk : bv);
  const int wm = w >> 1, wn = w & 1;
  const int srow = t >> 1, half = t & 1;

  f32x4 acc[4][4] = {};

  for (int kt = 0; kt < 12; ++kt) {
    __syncthreads();
    {
      const float4* ax = (const float4*)(X + (size_t)(m0 + srow) * 768 + kt * 64 + half * 32);
      const float4* bx = (const float4*)(W + (size_t)(n0 + srow) * 768 + kt * 64 + half * 32);
      #pragma unroll
      for (int j = 0; j < 4; ++j) {
        float4 a0 = ax[2 * j], a1 = ax[2 * j + 1];
        *(uint4*)(lds + swz(srow, half * 64 + j * 16, 128)) = cvt8(a0, a1);
        float4 b0 = bx[2 * j], b1 = bx[2 * j + 1];
        *(uint4*)(lds + 16384 + swz(srow, half * 64 + j * 16, 128)) = cvt8(b0, b1);
      }
    }
    __syncthreads();
    #pragma unroll
    for (int kk = 0; kk < 2; ++kk) {
      bf16x8 af[4], bfr[4];
      #pragma unroll
      for (int mi = 0; mi < 4; ++mi)
        af[mi] = *(const bf16x8*)(lds + swz(wm * 64 + mi * 16 + l15, kk * 64 + g * 16, 128));
      #pragma unroll
      for (int nj = 0; nj < 4; ++nj)
        bfr[nj] = *(const bf16x8*)(lds + 16384 + swz(wn * 64 + nj * 16 + l15, kk * 64 + g * 16, 128));
      #pragma unroll
      for (int mi = 0; mi < 4; ++mi)
        #pragma unroll
        for (int nj = 0; nj < 4; ++nj)
          acc[mi][nj] = MFMA16(af[mi], bfr[nj], acc[mi][nj]);
    }
  }

  #pragma unroll
  for (int mi = 0; mi < 4; ++mi) {
    #pragma unroll
    for (int nj = 0; nj < 4; ++nj) {
      const int nc = n0 + wn * 64 + nj * 16 + l15;  // [0,768)
      const int h = nc >> 6, d = nc & 63;
      const float bias = Bv[nc];
      const int mbase = m0 + wm * 64 + mi * 16 + g * 4;
      const int b = mbase >> 10, s = mbase & 1023;
      unsigned short u[4];
      #pragma unroll
      for (int r = 0; r < 4; ++r) {
        u[r] = f2bf(acc[mi][nj][r] + bias);
        qkv[(size_t)mat * NQ + (((size_t)(b * NHEAD + h)) * S_LEN + (s + r)) * 64 + d] = u[r];
      }
      if (mat == 2) {
        *(ushort4*)(vtout + (((size_t)(b * NHEAD + h)) * 64 + d) * S_LEN + s) =
            make_ushort4(u[0], u[1], u[2], u[3]);
      }
    }
  }
}

// ---------------------------------------------------------------------------
// Device part A: sym scores G = A A^T / 8 for A in {Q,K,V}.
// Row-streaming: block = 16 rows x 1024 cols = one CONTIGUOUS 64KB output
// region. Swapped-operand MFMA (lane owns a row); wave-private LDS transpose
// (^ (row<<5) swizzle, 2 lanes/bank) -> 512B-contiguous store instructions,
// 4 waves tile each 4KB row. No barriers. sid in [0, 9216).
// ---------------------------------------------------------------------------
__device__ __forceinline__ void sym_part(
    char* lds, int sid, const unsigned short* __restrict__ qkv,
    float* __restrict__ out)
{
  const int t = threadIdx.x, lane = t & 63, wv = t >> 6;
  const int g = lane >> 4, l15 = lane & 15;
  const int typ = sid / 3072, r2 = sid % 3072;
  const int bh = r2 >> 6, m0 = (r2 & 63) * 16;
  const unsigned short* M = qkv + (size_t)typ * NQ + (size_t)bh * 65536;
  float* O = out + (typ == 0 ? OFF_QRY : (typ == 1 ? OFF_KEY : OFF_VAL)) +
             (size_t)bh * 1048576;

  // A16 fragment (rows m0..m0+15), shared across all chunks
  const bf16x8 a0 = *(const bf16x8*)(M + (size_t)(m0 + l15) * 64 + g * 8);
  const bf16x8 a1 = *(const bf16x8*)(M + (size_t)(m0 + l15) * 64 + 32 + g * 8);

  char* STG = lds + wv * 8192;  // wave-private [16 rows][512B]
  const int colw = wv * 256;

  #pragma unroll
  for (int p = 0; p < 2; ++p) {
    // value(g,l15,r) = dot(A[colbase + g*4+r], A[m0+l15]) -> lane owns row l15
    f32x4 st[8];
    #pragma unroll
    for (int c = 0; c < 8; ++c) {
      const int rowb = colw + p * 128 + c * 16 + l15;
      const bf16x8 b0 = *(const bf16x8*)(M + (size_t)rowb * 64 + g * 8);
      const bf16x8 b1 = *(const bf16x8*)(M + (size_t)rowb * 64 + 32 + g * 8);
      f32x4 acc = {};
      acc = MFMA16(b0, a0, acc);
      acc = MFMA16(b1, a1, acc);
      st[c] = acc * 0.125f;
    }
    // transpose via wave-private LDS; phys = row*512 + (colbyte ^ (row<<5))
    #pragma unroll
    for (int c = 0; c < 8; ++c)
      *(f32x4*)(STG + l15 * 512 + ((c * 64 + g * 16) ^ (l15 << 5))) = st[c];
    if (typ == 2) {
      #pragma unroll
      for (int j = 0; j < 16; ++j) {
        const f32x2 v = *(const f32x2*)(STG + j * 512 + ((lane * 8) ^ (j << 5)));
        *(f32x2*)(O + (size_t)(m0 + j) * 1024 + colw + p * 128 + lane * 2) = v;
      }
    } else {
      #pragma unroll
      for (int j = 0; j < 16; ++j) {
        const f32x2 v = *(const f32x2*)(STG + j * 512 + ((lane * 8) ^ (j << 5)));
        float* rp = O + (size_t)(m0 + j) * 1024 + colw + p * 128 + lane * 2;
        rp[0] = v[0];
        rp[1] = v[1];
      }
    }
  }
}

// ---------------------------------------------------------------------------
// Device part B: fused attention_scores write + online softmax + context.
// S^T = mfma(K, Q) so each lane owns one q-row. fid in [0,768).
// ---------------------------------------------------------------------------
__device__ __forceinline__ void flash_part(
    char* lds, int fid, const unsigned short* __restrict__ qkv,
    const unsigned short* __restrict__ vt, const float* __restrict__ mask,
    float* __restrict__ out)
{
  const int t = threadIdx.x;
  const int lane = t & 63, w = t >> 6;
  const int g = lane >> 4, l15 = lane & 15;
  const int q0 = (fid & 15) * 64;
  const int bh = fid >> 4, b = bh / NHEAD, h = bh % NHEAD;
  const unsigned short* Qp  = qkv + (size_t)bh * (S_LEN * 64);
  const unsigned short* Kp  = qkv + NQ + (size_t)bh * (S_LEN * 64);
  const unsigned short* Vtp = vt + (size_t)bh * (S_LEN * 64);
  const int qrow = q0 + w * 16 + l15;  // this lane's q row

  bf16x8 qf[2];
  qf[0] = *(const bf16x8*)(Qp + (size_t)qrow * 64 + g * 8);
  qf[1] = *(const bf16x8*)(Qp + (size_t)qrow * 64 + 32 + g * 8);

  float m_run = -1e30f, l_run = 0.f;
  f32x4 o[4] = {};
  float* att = out + OFF_ATT + (size_t)bh * (1024ull * 1024) + (size_t)qrow * 1024;
  const float* mrow = mask + b * S_LEN;
  const int sr2 = t >> 1, hf = t & 1;  // K staging: 128 rows x 128B
  const int sr4 = t >> 2, qr = t & 3;  // Vt staging: 64 rows x 256B
  char* Plds = lds + 32768 + w * 4096;

  for (int kt = 0; kt < 8; ++kt) {
    __syncthreads();
    {
      const uint4* sk = (const uint4*)(Kp + (size_t)(kt * 128 + sr2) * 64 + hf * 32);
      #pragma unroll
      for (int j = 0; j < 4; ++j)
        *(uint4*)(lds + swz(sr2, hf * 64 + j * 16, 128)) = sk[j];
      const uint4* sv = (const uint4*)(Vtp + (size_t)sr4 * S_LEN + kt * 128 + qr * 32);
      #pragma unroll
      for (int j = 0; j < 4; ++j)
        *(uint4*)(lds + 16384 + swz(sr4, qr * 64 + j * 16, 256)) = sv[j];
    }
    __syncthreads();

    // S^T[k][q] = sum_d K[k][d] Q[q][d]
    f32x4 st[8] = {};
    #pragma unroll
    for (int kk = 0; kk < 2; ++kk)
      #pragma unroll
      for (int mi = 0; mi < 8; ++mi) {
        bf16x8 a = *(const bf16x8*)(lds + swz(mi * 16 + l15, kk * 64 + g * 16, 128));
        st[mi] = MFMA16(a, qf[kk], st[mi]);
      }

    // scale + mask + write scores (lane holds 4 consecutive k for its q row)
    float tmax = -1e30f;
    #pragma unroll
    for (int mi = 0; mi < 8; ++mi) {
      const f32x4 mk = *(const f32x4*)(mrow + kt * 128 + mi * 16 + g * 4);
      st[mi] = st[mi] * 0.125f + mk;
      *(f32x4*)(att + kt * 128 + mi * 16 + g * 4) = st[mi];
      #pragma unroll
      for (int r = 0; r < 4; ++r) tmax = fmaxf(tmax, st[mi][r]);
    }
    tmax = fmaxf(tmax, __shfl_xor(tmax, 16));
    tmax = fmaxf(tmax, __shfl_xor(tmax, 32));
    const float mnew = fmaxf(m_run, tmax);
    const float corr = __expf(m_run - mnew);
    float tsum = 0.f;
    #pragma unroll
    for (int mi = 0; mi < 8; ++mi)
      #pragma unroll
      for (int r = 0; r < 4; ++r) {
        const float p = __expf(st[mi][r] - mnew);
        st[mi][r] = p;
        tsum += p;
      }
    tsum += __shfl_xor(tsum, 16);
    tsum += __shfl_xor(tsum, 32);
    l_run = l_run * corr + tsum;
    m_run = mnew;
    #pragma unroll
    for (int dj = 0; dj < 4; ++dj) o[dj] *= corr;

    // P -> bf16 -> per-wave LDS [16 q rows][128 k], swizzled
    #pragma unroll
    for (int mi = 0; mi < 8; ++mi) {
      uint2 pw = make_uint2(pk2(st[mi][0], st[mi][1]), pk2(st[mi][2], st[mi][3]));
      *(uint2*)(Plds + swz(l15, mi * 32 + g * 8, 256)) = pw;
    }
    // O^T[d][q] += sum_k Vt[d][k] P[q][k]
    #pragma unroll
    for (int kk2 = 0; kk2 < 4; ++kk2) {
      const bf16x8 pa = *(const bf16x8*)(Plds + swz(l15, kk2 * 64 + g * 16, 256));
      #pragma unroll
      for (int dj = 0; dj < 4; ++dj) {
        const bf16x8 va = *(const bf16x8*)(lds + 16384 + swz(dj * 16 + l15, kk2 * 64 + g * 16, 256));
        o[dj] = MFMA16(va, pa, o[dj]);
      }
    }
  }

  const float inv = 1.f / l_run;
  #pragma unroll
  for (int dj = 0; dj < 4; ++dj) {
    f32x4 v = o[dj] * inv;
    *(f32x4*)(out + ((size_t)b * S_LEN + qrow) * 768 + h * 64 + dj * 16 + g * 4) = v;
  }
}

// ---------------------------------------------------------------------------
// Kernel 2: merged sym+flash. Grid 9984 = 9216 sym + 768 flash (every 13th).
// ---------------------------------------------------------------------------
__global__ __launch_bounds__(256) void fused_scores_attn_kernel(
    const unsigned short* __restrict__ qkv, const unsigned short* __restrict__ vt,
    const float* __restrict__ mask, float* __restrict__ out)
{
  __shared__ char lds[49152];
  const int bid = blockIdx.x;
  if (bid == 9983 && threadIdx.x == 0) out[OFF_CSC] = 0.f;
  if (bid % 13 == 0) {
    flash_part(lds, bid / 13, qkv, vt, mask, out);
  } else {
    sym_part(lds, bid - bid / 13 - 1, qkv, out);
  }
}

extern "C" void kernel_launch(void* const* d_in, const int* in_sizes, int n_in,
                              void* d_out, int out_size, void* d_ws, size_t ws_size,
                              hipStream_t stream) {
  (void)in_sizes; (void)n_in; (void)out_size; (void)ws_size;
  const float* X  = (const float*)d_in[0];
  const float* mk = (const float*)d_in[1];
  const float* Wq = (const float*)d_in[2];
  const float* bq = (const float*)d_in[3];
  const float* Wk = (const float*)d_in[4];
  const float* bk = (const float*)d_in[5];
  const float* Wv = (const float*)d_in[6];
  const float* bv = (const float*)d_in[7];
  float* out = (float*)d_out;
  unsigned short* qkv = (unsigned short*)d_ws;
  unsigned short* vt  = qkv + WS_VT;

  qkv_gemm_kernel<<<dim3(32, 18), 256, 0, stream>>>(X, Wq, Wk, Wv, bq, bk, bv, qkv, vt);
  fused_scores_attn_kernel<<<9984, 256, 0, stream>>>(qkv, vt, mk, out);
}

// Round 7
// 424.211 us; speedup vs baseline: 2.0739x; 1.0038x over previous
//
#include <hip/hip_runtime.h>
#include <hip/hip_bf16.h>
#include <stdint.h>

// Problem: B=4, S=1024, HID=768, H=12, D=64
#define S_LEN 1024
#define NHEAD 12
#define NQ 3145728LL  // B*H*S*D elements per Q/K/V matrix

// d_out element offsets (fp32), reference return order:
// context[4,1024,768], attention_scores[4,12,1024,1024], value_scores,
// context_score(scalar), query_scores, key_scores
static constexpr long long OFF_ATT = 3145728LL;
static constexpr long long OFF_VAL = 53477376LL;
static constexpr long long OFF_CSC = 103809024LL;
static constexpr long long OFF_QRY = 103809025LL;  // odd base (4B-aligned only)
static constexpr long long OFF_KEY = 154140673LL;  // odd base (4B-aligned only)

static constexpr long long WS_VT = 9437184LL;  // vt after qkv (3*NQ)

typedef short bf16x8 __attribute__((ext_vector_type(8)));
typedef float f32x4 __attribute__((ext_vector_type(4)));
// 4-byte-aligned float4: lets the compiler emit dword-aligned dwordx4 stores
// for the odd-offset qry/key outputs (worst case: splits to dwords = old code)
typedef float f32x4_a4 __attribute__((ext_vector_type(4), aligned(4)));

__device__ __forceinline__ unsigned short f2bf(float f) {
  return __builtin_bit_cast(unsigned short, __float2bfloat16(f));
}
__device__ __forceinline__ uint32_t pk2(float a, float b) {
  return (uint32_t)f2bf(a) | ((uint32_t)f2bf(b) << 16);
}
__device__ __forceinline__ uint4 cvt8(float4 a, float4 b) {
  return make_uint4(pk2(a.x, a.y), pk2(a.z, a.w), pk2(b.x, b.y), pk2(b.z, b.w));
}
// XOR swizzle on 16B chunks within a row; stride >= 128 bytes.
__device__ __forceinline__ uint32_t swz(uint32_t row, uint32_t col_bytes, uint32_t stride) {
  return row * stride + (col_bytes ^ ((row & 7u) << 4));
}
#define MFMA16(a, b, c) __builtin_amdgcn_mfma_f32_16x16x32_bf16((a), (b), (c), 0, 0, 0)

// ---------------------------------------------------------------------------
// Kernel 1: Y = X @ W^T + bias (fp32 in, bf16 staged). 128x128 tile, BK=64.
// Writes bf16 Q/K/V [B,H,S,D] and Vt [B,H,D,S]. Grid (32, 18).
// ---------------------------------------------------------------------------
__global__ __launch_bounds__(256) void qkv_gemm_kernel(
    const float* __restrict__ X,
    const float* __restrict__ Wq, const float* __restrict__ Wk,
    const float* __restrict__ Wv,
    const float* __restrict__ bq, const float* __restrict__ bk,
    const float* __restrict__ bv,
    unsigned short* __restrict__ qkv, unsigned short* __restrict__ vtout)
{
  __shared__ char lds[32768];
  const int t = threadIdx.x;
  const int lane = t & 63, w = t >> 6;
  const int g = lane >> 4, l15 = lane & 15;
  const int m0 = blockIdx.x * 128;
  const int mat = blockIdx.y / 6;
  const int n0 = (blockIdx.y % 6) * 128;
  const float* W  = mat == 0 ? Wq : (mat == 1 ? Wk : Wv);
  const float* Bv = mat == 0 ? bq : (mat == 1 ? bk : bv);
  const int wm = w >> 1, wn = w & 1;
  const int srow = t >> 1, half = t & 1;

  f32x4 acc[4][4] = {};

  for (int kt = 0; kt < 12; ++kt) {
    __syncthreads();
    {
      const float4* ax = (const float4*)(X + (size_t)(m0 + srow) * 768 + kt * 64 + half * 32);
      const float4* bx = (const float4*)(W + (size_t)(n0 + srow) * 768 + kt * 64 + half * 32);
      #pragma unroll
      for (int j = 0; j < 4; ++j) {
        float4 a0 = ax[2 * j], a1 = ax[2 * j + 1];
        *(uint4*)(lds + swz(srow, half * 64 + j * 16, 128)) = cvt8(a0, a1);
        float4 b0 = bx[2 * j], b1 = bx[2 * j + 1];
        *(uint4*)(lds + 16384 + swz(srow, half * 64 + j * 16, 128)) = cvt8(b0, b1);
      }
    }
    __syncthreads();
    #pragma unroll
    for (int kk = 0; kk < 2; ++kk) {
      bf16x8 af[4], bfr[4];
      #pragma unroll
      for (int mi = 0; mi < 4; ++mi)
        af[mi] = *(const bf16x8*)(lds + swz(wm * 64 + mi * 16 + l15, kk * 64 + g * 16, 128));
      #pragma unroll
      for (int nj = 0; nj < 4; ++nj)
        bfr[nj] = *(const bf16x8*)(lds + 16384 + swz(wn * 64 + nj * 16 + l15, kk * 64 + g * 16, 128));
      #pragma unroll
      for (int mi = 0; mi < 4; ++mi)
        #pragma unroll
        for (int nj = 0; nj < 4; ++nj)
          acc[mi][nj] = MFMA16(af[mi], bfr[nj], acc[mi][nj]);
    }
  }

  #pragma unroll
  for (int mi = 0; mi < 4; ++mi) {
    #pragma unroll
    for (int nj = 0; nj < 4; ++nj) {
      const int nc = n0 + wn * 64 + nj * 16 + l15;  // [0,768)
      const int h = nc >> 6, d = nc & 63;
      const float bias = Bv[nc];
      const int mbase = m0 + wm * 64 + mi * 16 + g * 4;
      const int b = mbase >> 10, s = mbase & 1023;
      unsigned short u[4];
      #pragma unroll
      for (int r = 0; r < 4; ++r) {
        u[r] = f2bf(acc[mi][nj][r] + bias);
        qkv[(size_t)mat * NQ + (((size_t)(b * NHEAD + h)) * S_LEN + (s + r)) * 64 + d] = u[r];
      }
      if (mat == 2) {
        *(ushort4*)(vtout + (((size_t)(b * NHEAD + h)) * 64 + d) * S_LEN + s) =
            make_ushort4(u[0], u[1], u[2], u[3]);
      }
    }
  }
}

// ---------------------------------------------------------------------------
// Device part A: sym scores G = A A^T / 8 for A in {Q,K,V}.
// 128x128 tile; 4 waves of 64x64; LDS-tiled, 2 barriers (R2 structure).
// ALL outputs use the symmetric-transpose store (G[m][n] -> O[n*1024+m]):
// bitwise-exact by MFMA operand commutativity. value: aligned float4;
// qry/key: 4B-aligned float4 (dword-aligned dwordx4).
// ---------------------------------------------------------------------------
__device__ __forceinline__ void sym_part(
    char* lds, int sid, const unsigned short* __restrict__ qkv,
    float* __restrict__ out)
{
  const int t = threadIdx.x;
  const int lane = t & 63, w = t >> 6;
  const int g = lane >> 4, l15 = lane & 15;
  const int m0 = (sid & 7) * 128;
  const int n0 = ((sid >> 3) & 7) * 128;
  const int bz = sid >> 6;           // 0..143
  const int typ = bz / 48, bh = bz % 48;
  const unsigned short* A = qkv + (size_t)typ * NQ + (size_t)bh * (S_LEN * 64);
  const int srow = t >> 1, hf = t & 1;
  {
    const uint4* sa = (const uint4*)(A + (size_t)(m0 + srow) * 64 + hf * 32);
    #pragma unroll
    for (int j = 0; j < 4; ++j)
      *(uint4*)(lds + swz(srow, hf * 64 + j * 16, 128)) = sa[j];
    const uint4* sb = (const uint4*)(A + (size_t)(n0 + srow) * 64 + hf * 32);
    #pragma unroll
    for (int j = 0; j < 4; ++j)
      *(uint4*)(lds + 16384 + swz(srow, hf * 64 + j * 16, 128)) = sb[j];
  }
  __syncthreads();
  const int wm = w >> 1, wn = w & 1;
  f32x4 acc[4][4] = {};
  #pragma unroll
  for (int kk = 0; kk < 2; ++kk) {
    bf16x8 af[4], bfr[4];
    #pragma unroll
    for (int mi = 0; mi < 4; ++mi)
      af[mi] = *(const bf16x8*)(lds + swz(wm * 64 + mi * 16 + l15, kk * 64 + g * 16, 128));
    #pragma unroll
    for (int nj = 0; nj < 4; ++nj)
      bfr[nj] = *(const bf16x8*)(lds + 16384 + swz(wn * 64 + nj * 16 + l15, kk * 64 + g * 16, 128));
    #pragma unroll
    for (int mi = 0; mi < 4; ++mi)
      #pragma unroll
      for (int nj = 0; nj < 4; ++nj)
        acc[mi][nj] = MFMA16(af[mi], bfr[nj], acc[mi][nj]);
  }
  // Symmetric-transpose stores; nj outer so consecutive instructions fill
  // consecutive 64B m-chunks of the same output row n.
  if (typ == 2) {
    float* O = out + OFF_VAL + (size_t)bh * (1024ull * 1024);
    #pragma unroll
    for (int nj = 0; nj < 4; ++nj)
      #pragma unroll
      for (int mi = 0; mi < 4; ++mi) {
        f32x4 v = acc[mi][nj] * 0.125f;
        *(f32x4*)(O + (size_t)(n0 + wn * 64 + nj * 16 + l15) * 1024 +
                  (m0 + wm * 64 + mi * 16 + g * 4)) = v;
      }
  } else {
    float* O = out + (typ == 0 ? OFF_QRY : OFF_KEY) + (size_t)bh * (1024ull * 1024);
    #pragma unroll
    for (int nj = 0; nj < 4; ++nj)
      #pragma unroll
      for (int mi = 0; mi < 4; ++mi) {
        f32x4 v = acc[mi][nj] * 0.125f;
        *(f32x4_a4*)(O + (size_t)(n0 + wn * 64 + nj * 16 + l15) * 1024 +
                     (m0 + wm * 64 + mi * 16 + g * 4)) = v;
      }
  }
}

// ---------------------------------------------------------------------------
// Device part B: fused attention_scores write + online softmax + context.
// S^T = mfma(K, Q) so each lane owns one q-row. fid in [0,768).
// K staged in LDS (reused by all 4 waves); V frags direct from L2-resident
// vt (no staging); P per-wave in LDS. Total LDS use: 32KB.
// ---------------------------------------------------------------------------
__device__ __forceinline__ void flash_part(
    char* lds, int fid, const unsigned short* __restrict__ qkv,
    const unsigned short* __restrict__ vt, const float* __restrict__ mask,
    float* __restrict__ out)
{
  const int t = threadIdx.x;
  const int lane = t & 63, w = t >> 6;
  const int g = lane >> 4, l15 = lane & 15;
  const int q0 = (fid & 15) * 64;
  const int bh = fid >> 4, b = bh / NHEAD, h = bh % NHEAD;
  const unsigned short* Qp  = qkv + (size_t)bh * (S_LEN * 64);
  const unsigned short* Kp  = qkv + NQ + (size_t)bh * (S_LEN * 64);
  const unsigned short* Vtp = vt + (size_t)bh * (S_LEN * 64);
  const int qrow = q0 + w * 16 + l15;  // this lane's q row

  bf16x8 qf[2];
  qf[0] = *(const bf16x8*)(Qp + (size_t)qrow * 64 + g * 8);
  qf[1] = *(const bf16x8*)(Qp + (size_t)qrow * 64 + 32 + g * 8);

  float m_run = -1e30f, l_run = 0.f;
  f32x4 o[4] = {};
  float* att = out + OFF_ATT + (size_t)bh * (1024ull * 1024) + (size_t)qrow * 1024;
  const float* mrow = mask + b * S_LEN;
  const int sr2 = t >> 1, hf = t & 1;  // K staging: 128 rows x 128B
  char* Plds = lds + 16384 + w * 4096;

  for (int kt = 0; kt < 8; ++kt) {
    __syncthreads();
    {
      const uint4* sk = (const uint4*)(Kp + (size_t)(kt * 128 + sr2) * 64 + hf * 32);
      #pragma unroll
      for (int j = 0; j < 4; ++j)
        *(uint4*)(lds + swz(sr2, hf * 64 + j * 16, 128)) = sk[j];
    }
    __syncthreads();

    // S^T[k][q] = sum_d K[k][d] Q[q][d]
    f32x4 st[8] = {};
    #pragma unroll
    for (int kk = 0; kk < 2; ++kk)
      #pragma unroll
      for (int mi = 0; mi < 8; ++mi) {
        bf16x8 a = *(const bf16x8*)(lds + swz(mi * 16 + l15, kk * 64 + g * 16, 128));
        st[mi] = MFMA16(a, qf[kk], st[mi]);
      }

    // scale + mask + write scores (lane holds 4 consecutive k for its q row)
    float tmax = -1e30f;
    #pragma unroll
    for (int mi = 0; mi < 8; ++mi) {
      const f32x4 mk = *(const f32x4*)(mrow + kt * 128 + mi * 16 + g * 4);
      st[mi] = st[mi] * 0.125f + mk;
      *(f32x4*)(att + kt * 128 + mi * 16 + g * 4) = st[mi];
      #pragma unroll
      for (int r = 0; r < 4; ++r) tmax = fmaxf(tmax, st[mi][r]);
    }
    tmax = fmaxf(tmax, __shfl_xor(tmax, 16));
    tmax = fmaxf(tmax, __shfl_xor(tmax, 32));
    const float mnew = fmaxf(m_run, tmax);
    const float corr = __expf(m_run - mnew);
    float tsum = 0.f;
    #pragma unroll
    for (int mi = 0; mi < 8; ++mi)
      #pragma unroll
      for (int r = 0; r < 4; ++r) {
        const float p = __expf(st[mi][r] - mnew);
        st[mi][r] = p;
        tsum += p;
      }
    tsum += __shfl_xor(tsum, 16);
    tsum += __shfl_xor(tsum, 32);
    l_run = l_run * corr + tsum;
    m_run = mnew;
    #pragma unroll
    for (int dj = 0; dj < 4; ++dj) o[dj] *= corr;

    // P -> bf16 -> per-wave LDS [16 q rows][128 k], swizzled
    #pragma unroll
    for (int mi = 0; mi < 8; ++mi) {
      uint2 pw = make_uint2(pk2(st[mi][0], st[mi][1]), pk2(st[mi][2], st[mi][3]));
      *(uint2*)(Plds + swz(l15, mi * 32 + g * 8, 256)) = pw;
    }
    // O^T[d][q] += sum_k Vt[d][k] P[q][k]; V frags direct from global vt
    #pragma unroll
    for (int kk2 = 0; kk2 < 4; ++kk2) {
      const bf16x8 pa = *(const bf16x8*)(Plds + swz(l15, kk2 * 64 + g * 16, 256));
      #pragma unroll
      for (int dj = 0; dj < 4; ++dj) {
        const bf16x8 vf = *(const bf16x8*)(Vtp + (size_t)(dj * 16 + l15) * 1024 +
                                           kt * 128 + kk2 * 32 + g * 8);
        o[dj] = MFMA16(vf, pa, o[dj]);
      }
    }
  }

  const float inv = 1.f / l_run;
  #pragma unroll
  for (int dj = 0; dj < 4; ++dj) {
    f32x4 v = o[dj] * inv;
    *(f32x4*)(out + ((size_t)b * S_LEN + qrow) * 768 + h * 64 + dj * 16 + g * 4) = v;
  }
}

// ---------------------------------------------------------------------------
// Kernel 2: merged sym+flash. Grid 9984 = 768*13; every 13th block is flash.
// 32KB LDS -> 5 blocks/CU.
// ---------------------------------------------------------------------------
__global__ __launch_bounds__(256) void fused_scores_attn_kernel(
    const unsigned short* __restrict__ qkv, const unsigned short* __restrict__ vt,
    const float* __restrict__ mask, float* __restrict__ out)
{
  __shared__ char lds[32768];
  const int bid = blockIdx.x;
  if (bid == 9983 && threadIdx.x == 0) out[OFF_CSC] = 0.f;
  if (bid % 13 == 0) {
    flash_part(lds, bid / 13, qkv, vt, mask, out);
  } else {
    sym_part(lds, bid - bid / 13 - 1, qkv, out);
  }
}

extern "C" void kernel_launch(void* const* d_in, const int* in_sizes, int n_in,
                              void* d_out, int out_size, void* d_ws, size_t ws_size,
                              hipStream_t stream) {
  (void)in_sizes; (void)n_in; (void)out_size; (void)ws_size;
  const float* X  = (const float*)d_in[0];
  const float* mk = (const float*)d_in[1];
  const float* Wq = (const float*)d_in[2];
  const float* bq = (const float*)d_in[3];
  const float* Wk = (const float*)d_in[4];
  const float* bk = (const float*)d_in[5];
  const float* Wv = (const float*)d_in[6];
  const float* bv = (const float*)d_in[7];
  float* out = (float*)d_out;
  unsigned short* qkv = (unsigned short*)d_ws;
  unsigned short* vt  = qkv + WS_VT;

  qkv_gemm_kernel<<<dim3(32, 18), 256, 0, stream>>>(X, Wq, Wk, Wv, bq, bk, bv, qkv, vt);
  fused_scores_attn_kernel<<<9984, 256, 0, stream>>>(qkv, vt, mk, out);
}

// Round 8
// 307.328 us; speedup vs baseline: 2.8627x; 1.3803x over previous
//
#include <hip/hip_runtime.h>
#include <hip/hip_bf16.h>
#include <stdint.h>

// Problem: B=4, S=1024, HID=768, H=12, D=64
#define S_LEN 1024
#define NHEAD 12
#define NQ 3145728LL  // B*H*S*D elements per Q/K/V matrix

// d_out element offsets (fp32), in reference return order:
// context[4,1024,768], attention_scores[4,12,1024,1024], value_scores,
// context_score(scalar), query_scores, key_scores
static constexpr long long OFF_ATT = 3145728LL;
static constexpr long long OFF_VAL = 53477376LL;
static constexpr long long OFF_CSC = 103809024LL;
static constexpr long long OFF_QRY = 103809025LL;  // odd -> dword stores only
static constexpr long long OFF_KEY = 154140673LL;  // odd -> dword stores only

// ws layout (bf16 element offsets)
static constexpr long long WS_VT = 9437184LL;   // after qkv (3*NQ)
static constexpr long long WS_XB = 12582912LL;  // bf16 X [4096][768]
static constexpr long long WS_WB = 15728640LL;  // bf16 W concat [2304][768]

typedef short bf16x8 __attribute__((ext_vector_type(8)));
typedef float f32x4 __attribute__((ext_vector_type(4)));

__device__ __forceinline__ unsigned short f2bf(float f) {
  return __builtin_bit_cast(unsigned short, __float2bfloat16(f));
}
__device__ __forceinline__ uint32_t pk2(float a, float b) {
  return (uint32_t)f2bf(a) | ((uint32_t)f2bf(b) << 16);
}
__device__ __forceinline__ uint4 cvt8(float4 a, float4 b) {
  return make_uint4(pk2(a.x, a.y), pk2(a.z, a.w), pk2(b.x, b.y), pk2(b.z, b.w));
}
// XOR swizzle on 16B chunks within a row; stride must be >=128 bytes.
__device__ __forceinline__ uint32_t swz(uint32_t row, uint32_t col_bytes, uint32_t stride) {
  return row * stride + (col_bytes ^ ((row & 7u) << 4));
}
#define MFMA16(a, b, c) __builtin_amdgcn_mfma_f32_16x16x32_bf16((a), (b), (c), 0, 0, 0)

// ---------------------------------------------------------------------------
// Kernel 0: fp32 -> bf16 pre-convert of X and Wq|Wk|Wv into workspace.
// Grid 2400 x 256; each thread converts 8 elements (2x float4 -> uint4).
// ---------------------------------------------------------------------------
__global__ __launch_bounds__(256) void tobf16_kernel(
    const float* __restrict__ X, const float* __restrict__ Wq,
    const float* __restrict__ Wk, const float* __restrict__ Wv,
    unsigned short* __restrict__ xb)
{
  const int bx = blockIdx.x;
  const float* src;
  unsigned short* dst;
  long long base;
  if (bx < 1536)      { src = X;  dst = xb;                      base = (long long)bx * 2048; }
  else if (bx < 1824) { src = Wq; dst = xb + (WS_WB - WS_XB);    base = (long long)(bx - 1536) * 2048; }
  else if (bx < 2112) { src = Wk; dst = xb + (WS_WB - WS_XB) + 589824;     base = (long long)(bx - 1824) * 2048; }
  else                { src = Wv; dst = xb + (WS_WB - WS_XB) + 2 * 589824; base = (long long)(bx - 2112) * 2048; }
  const long long i = base + (long long)threadIdx.x * 8;
  float4 a = *(const float4*)(src + i);
  float4 b = *(const float4*)(src + i + 4);
  *(uint4*)(dst + i) = cvt8(a, b);
}

// ---------------------------------------------------------------------------
// Kernel 1: Y = Xb @ Wb^T + bias. 128x128 tiles, BK=64, 12 k-iters, 4 waves
// (each 64x64 = 4x4 frags). Writes bf16 Q/K/V [B,H,S,D] and Vt [B,H,D,S].
// Grid (32, 18).
// ---------------------------------------------------------------------------
__global__ __launch_bounds__(256) void qkv_gemm_kernel(
    const unsigned short* __restrict__ Xb, const unsigned short* __restrict__ Wb,
    const float* __restrict__ B0, const float* __restrict__ B1,
    const float* __restrict__ B2,
    unsigned short* __restrict__ qkv, unsigned short* __restrict__ vt)
{
  __shared__ char lds[32768];  // A tile [128][64] bf16 (16KB) + B tile (16KB)
  const int t = threadIdx.x;
  const int lane = t & 63, w = t >> 6;
  const int g = lane >> 4, l15 = lane & 15;
  const int m0 = blockIdx.x * 128;
  const int n0 = blockIdx.y * 128;  // global col in [0,2304); never crosses a 768-mat
  const int wm = w >> 1, wn = w & 1;
  const int srow = t >> 1, sch0 = (t & 1) * 4;

  f32x4 acc[4][4] = {};

  for (int kt = 0; kt < 12; ++kt) {
    __syncthreads();
    #pragma unroll
    for (int j = 0; j < 4; ++j) {
      uint4 a = *(const uint4*)(Xb + (size_t)(m0 + srow) * 768 + kt * 64 + (sch0 + j) * 8);
      *(uint4*)(lds + swz(srow, (sch0 + j) * 16, 128)) = a;
      uint4 b = *(const uint4*)(Wb + (size_t)(n0 + srow) * 768 + kt * 64 + (sch0 + j) * 8);
      *(uint4*)(lds + 16384 + swz(srow, (sch0 + j) * 16, 128)) = b;
    }
    __syncthreads();
    #pragma unroll
    for (int kk = 0; kk < 2; ++kk) {
      bf16x8 af[4], bfr[4];
      #pragma unroll
      for (int mi = 0; mi < 4; ++mi)
        af[mi] = *(const bf16x8*)(lds + swz(wm * 64 + mi * 16 + l15, kk * 64 + g * 16, 128));
      #pragma unroll
      for (int nj = 0; nj < 4; ++nj)
        bfr[nj] = *(const bf16x8*)(lds + 16384 + swz(wn * 64 + nj * 16 + l15, kk * 64 + g * 16, 128));
      #pragma unroll
      for (int mi = 0; mi < 4; ++mi)
        #pragma unroll
        for (int nj = 0; nj < 4; ++nj)
          acc[mi][nj] = MFMA16(af[mi], bfr[nj], acc[mi][nj]);
    }
  }

  #pragma unroll
  for (int mi = 0; mi < 4; ++mi) {
    #pragma unroll
    for (int nj = 0; nj < 4; ++nj) {
      const int ncg = n0 + wn * 64 + nj * 16 + l15;  // [0,2304)
      const int mat = ncg / 768, nc = ncg % 768;
      const int h = nc >> 6, d = nc & 63;
      const float bias = (mat == 0 ? B0 : (mat == 1 ? B1 : B2))[nc];
      const int mbase = m0 + wm * 64 + mi * 16 + g * 4;  // 4 consecutive rows
      const int b = mbase >> 10, s = mbase & 1023;
      unsigned short u[4];
      #pragma unroll
      for (int r = 0; r < 4; ++r) {
        u[r] = f2bf(acc[mi][nj][r] + bias);
        qkv[(size_t)mat * NQ + (((size_t)(b * NHEAD + h)) * S_LEN + (s + r)) * 64 + d] = u[r];
      }
      if (mat == 2) {  // transposed V for the PV step
        *(ushort4*)(vt + (((size_t)(b * NHEAD + h)) * 64 + d) * S_LEN + s) =
            make_ushort4(u[0], u[1], u[2], u[3]);
      }
    }
  }
}

// ---------------------------------------------------------------------------
// Device part A: sym scores G = A A^T / 8 for A in {Q,K,V}.
// 128x128 tile per call; 4 waves of 64x64.
// ---------------------------------------------------------------------------
__device__ __forceinline__ void sym_part(
    char* lds, int sid, const unsigned short* __restrict__ qkv,
    float* __restrict__ out)
{
  const int t = threadIdx.x;
  const int lane = t & 63, w = t >> 6;
  const int g = lane >> 4, l15 = lane & 15;
  const int m0 = (sid & 7) * 128;
  const int n0 = ((sid >> 3) & 7) * 128;
  const int bz = sid >> 6;           // 0..143
  const int typ = bz / 48, bh = bz % 48;
  const unsigned short* A = qkv + (size_t)typ * NQ + (size_t)bh * (S_LEN * 64);
  const int srow = t >> 1, hf = t & 1;
  {
    const uint4* sa = (const uint4*)(A + (size_t)(m0 + srow) * 64 + hf * 32);
    #pragma unroll
    for (int j = 0; j < 4; ++j)
      *(uint4*)(lds + swz(srow, hf * 64 + j * 16, 128)) = sa[j];
    const uint4* sb = (const uint4*)(A + (size_t)(n0 + srow) * 64 + hf * 32);
    #pragma unroll
    for (int j = 0; j < 4; ++j)
      *(uint4*)(lds + 16384 + swz(srow, hf * 64 + j * 16, 128)) = sb[j];
  }
  __syncthreads();
  const int wm = w >> 1, wn = w & 1;
  f32x4 acc[4][4] = {};
  #pragma unroll
  for (int kk = 0; kk < 2; ++kk) {
    bf16x8 af[4], bfr[4];
    #pragma unroll
    for (int mi = 0; mi < 4; ++mi)
      af[mi] = *(const bf16x8*)(lds + swz(wm * 64 + mi * 16 + l15, kk * 64 + g * 16, 128));
    #pragma unroll
    for (int nj = 0; nj < 4; ++nj)
      bfr[nj] = *(const bf16x8*)(lds + 16384 + swz(wn * 64 + nj * 16 + l15, kk * 64 + g * 16, 128));
    #pragma unroll
    for (int mi = 0; mi < 4; ++mi)
      #pragma unroll
      for (int nj = 0; nj < 4; ++nj)
        acc[mi][nj] = MFMA16(af[mi], bfr[nj], acc[mi][nj]);
  }
  if (typ == 2) {
    // Symmetry trick: store frag at the TRANSPOSED location -> float4 stores.
    float* O = out + OFF_VAL + (size_t)bh * (1024ull * 1024);
    #pragma unroll
    for (int mi = 0; mi < 4; ++mi)
      #pragma unroll
      for (int nj = 0; nj < 4; ++nj) {
        f32x4 v = acc[mi][nj] * 0.125f;
        *(f32x4*)(O + (size_t)(n0 + wn * 64 + nj * 16 + l15) * 1024 +
                  (m0 + wm * 64 + mi * 16 + g * 4)) = v;
      }
  } else {
    float* O = out + (typ == 0 ? OFF_QRY : OFF_KEY) + (size_t)bh * (1024ull * 1024);
    #pragma unroll
    for (int mi = 0; mi < 4; ++mi)
      #pragma unroll
      for (int nj = 0; nj < 4; ++nj)
        #pragma unroll
        for (int r = 0; r < 4; ++r)
          O[(size_t)(m0 + wm * 64 + mi * 16 + g * 4 + r) * 1024 +
            (n0 + wn * 64 + nj * 16 + l15)] = acc[mi][nj][r] * 0.125f;
  }
}

// ---------------------------------------------------------------------------
// Device part B: fused attention_scores write + online softmax + context.
// S^T = mfma(K, Q) so each lane owns one q-row. fid in [0,768).
// ---------------------------------------------------------------------------
__device__ __forceinline__ void flash_part(
    char* lds, int fid, const unsigned short* __restrict__ qkv,
    const unsigned short* __restrict__ vt, const float* __restrict__ mask,
    float* __restrict__ out)
{
  const int t = threadIdx.x;
  const int lane = t & 63, w = t >> 6;
  const int g = lane >> 4, l15 = lane & 15;
  const int q0 = (fid & 15) * 64;
  const int bh = fid >> 4, b = bh / NHEAD, h = bh % NHEAD;
  const unsigned short* Qp  = qkv + (size_t)bh * (S_LEN * 64);
  const unsigned short* Kp  = qkv + NQ + (size_t)bh * (S_LEN * 64);
  const unsigned short* Vtp = vt + (size_t)bh * (S_LEN * 64);
  const int qrow = q0 + w * 16 + l15;  // this lane's q row

  bf16x8 qf[2];
  qf[0] = *(const bf16x8*)(Qp + (size_t)qrow * 64 + g * 8);
  qf[1] = *(const bf16x8*)(Qp + (size_t)qrow * 64 + 32 + g * 8);

  float m_run = -1e30f, l_run = 0.f;
  f32x4 o[4] = {};
  float* att = out + OFF_ATT + (size_t)bh * (1024ull * 1024) + (size_t)qrow * 1024;
  const float* mrow = mask + b * S_LEN;
  const int sr2 = t >> 1, hf = t & 1;  // K staging: 128 rows x 128B
  const int sr4 = t >> 2, qr = t & 3;  // Vt staging: 64 rows x 256B
  char* Plds = lds + 32768 + w * 4096;

  for (int kt = 0; kt < 8; ++kt) {
    __syncthreads();
    {
      const uint4* sk = (const uint4*)(Kp + (size_t)(kt * 128 + sr2) * 64 + hf * 32);
      #pragma unroll
      for (int j = 0; j < 4; ++j)
        *(uint4*)(lds + swz(sr2, hf * 64 + j * 16, 128)) = sk[j];
      const uint4* sv = (const uint4*)(Vtp + (size_t)sr4 * S_LEN + kt * 128 + qr * 32);
      #pragma unroll
      for (int j = 0; j < 4; ++j)
        *(uint4*)(lds + 16384 + swz(sr4, qr * 64 + j * 16, 256)) = sv[j];
    }
    __syncthreads();

    // S^T[k][q] = sum_d K[k][d] Q[q][d]
    f32x4 st[8] = {};
    #pragma unroll
    for (int kk = 0; kk < 2; ++kk)
      #pragma unroll
      for (int mi = 0; mi < 8; ++mi) {
        bf16x8 a = *(const bf16x8*)(lds + swz(mi * 16 + l15, kk * 64 + g * 16, 128));
        st[mi] = MFMA16(a, qf[kk], st[mi]);
      }

    // scale + mask + write scores (lane holds 4 consecutive k for its q row)
    float tmax = -1e30f;
    #pragma unroll
    for (int mi = 0; mi < 8; ++mi) {
      f32x4 mk = *(const f32x4*)(mrow + kt * 128 + mi * 16 + g * 4);
      st[mi] = st[mi] * 0.125f + mk;
      *(f32x4*)(att + kt * 128 + mi * 16 + g * 4) = st[mi];
      #pragma unroll
      for (int r = 0; r < 4; ++r) tmax = fmaxf(tmax, st[mi][r]);
    }
    tmax = fmaxf(tmax, __shfl_xor(tmax, 16));
    tmax = fmaxf(tmax, __shfl_xor(tmax, 32));
    const float mnew = fmaxf(m_run, tmax);
    const float corr = __expf(m_run - mnew);
    float tsum = 0.f;
    #pragma unroll
    for (int mi = 0; mi < 8; ++mi)
      #pragma unroll
      for (int r = 0; r < 4; ++r) {
        float p = __expf(st[mi][r] - mnew);
        st[mi][r] = p;
        tsum += p;
      }
    tsum += __shfl_xor(tsum, 16);
    tsum += __shfl_xor(tsum, 32);
    l_run = l_run * corr + tsum;
    m_run = mnew;
    #pragma unroll
    for (int dj = 0; dj < 4; ++dj) o[dj] *= corr;

    // P -> bf16 -> per-wave LDS [16 q rows][128 k], swizzled
    #pragma unroll
    for (int mi = 0; mi < 8; ++mi) {
      uint2 pw = make_uint2(pk2(st[mi][0], st[mi][1]), pk2(st[mi][2], st[mi][3]));
      *(uint2*)(Plds + swz(l15, mi * 32 + g * 8, 256)) = pw;
    }
    // O^T[d][q] += sum_k Vt[d][k] P[q][k]
    #pragma unroll
    for (int kk2 = 0; kk2 < 4; ++kk2) {
      bf16x8 pa = *(const bf16x8*)(Plds + swz(l15, kk2 * 64 + g * 16, 256));
      #pragma unroll
      for (int dj = 0; dj < 4; ++dj) {
        bf16x8 va = *(const bf16x8*)(lds + 16384 + swz(dj * 16 + l15, kk2 * 64 + g * 16, 256));
        o[dj] = MFMA16(va, pa, o[dj]);
      }
    }
  }

  const float inv = 1.f / l_run;
  #pragma unroll
  for (int dj = 0; dj < 4; ++dj) {
    f32x4 v = o[dj] * inv;
    *(f32x4*)(out + ((size_t)b * S_LEN + qrow) * 768 + h * 64 + dj * 16 + g * 4) = v;
  }
}

// ---------------------------------------------------------------------------
// Kernel 2: merged sym+flash. Grid 9984 = 768*13. Every 13th block is a flash
// block so write-bound sym blocks and compute-phase flash blocks co-reside on
// each CU, hiding flash compute under the HBM write stream.
// ---------------------------------------------------------------------------
__global__ __launch_bounds__(256) void fused_scores_attn_kernel(
    const unsigned short* __restrict__ qkv, const unsigned short* __restrict__ vt,
    const float* __restrict__ mask, float* __restrict__ out)
{
  __shared__ char lds[49152];
  const int bid = blockIdx.x;
  if (bid == 9983 && threadIdx.x == 0) out[OFF_CSC] = 0.f;
  if (bid % 13 == 0) {
    flash_part(lds, bid / 13, qkv, vt, mask, out);
  } else {
    sym_part(lds, bid - bid / 13 - 1, qkv, out);
  }
}

extern "C" void kernel_launch(void* const* d_in, const int* in_sizes, int n_in,
                              void* d_out, int out_size, void* d_ws, size_t ws_size,
                              hipStream_t stream) {
  (void)in_sizes; (void)n_in; (void)out_size; (void)ws_size;
  const float* X  = (const float*)d_in[0];
  const float* mk = (const float*)d_in[1];
  const float* Wq = (const float*)d_in[2];
  const float* bq = (const float*)d_in[3];
  const float* Wk = (const float*)d_in[4];
  const float* bk = (const float*)d_in[5];
  const float* Wv = (const float*)d_in[6];
  const float* bv = (const float*)d_in[7];
  float* out = (float*)d_out;
  unsigned short* ws = (unsigned short*)d_ws;
  unsigned short* qkv = ws;            // bf16 Q|K|V [B,H,S,D]
  unsigned short* vt  = ws + WS_VT;    // bf16 Vt [B,H,D,S]
  unsigned short* xb  = ws + WS_XB;    // bf16 X, then W concat at WS_WB

  tobf16_kernel<<<2400, 256, 0, stream>>>(X, Wq, Wk, Wv, xb);
  qkv_gemm_kernel<<<dim3(32, 18), 256, 0, stream>>>(xb, ws + WS_WB, bq, bk, bv, qkv, vt);
  fused_scores_attn_kernel<<<9984, 256, 0, stream>>>(qkv, vt, mk, out);
}